// Round 3
// baseline (11374.329 us; speedup 1.0000x reference)
//
#include <hip/hip_runtime.h>
#include <hip/hip_bf16.h>
#include <stdint.h>

#define NGRAPH 16
#define EPSV 1e-5f
#define SLOPE 0.01f

// ws float-offset layout (stats area zeroed each launch)
#define OFF_SUM1 0        // [16][128]
#define OFF_SQ1  2048     // [16][128]
#define OFF_CNT  4096     // [16]
#define OFF_SUM2 4112     // [16][64]
#define OFF_SQ2  5136     // [16][64]
#define OFF_A1   6160     // [16][128]
#define OFF_C1   8208     // [16][128]
#define OFF_A2   10256    // [16][64]
#define OFF_C2   11280    // [16][64]
#define ZERO_FLOATS 6160  // sum1,sq1,cnt,sum2,sq2 must start at 0
#define H2_BYTE_OFF 65536 // bf16 h2 buffer lives here (N*32 dwords)

// monotone float->uint encoding: uint order == float order
__device__ __forceinline__ unsigned int enc_f32(float f) {
  unsigned int b = __float_as_uint(f);
  return (b & 0x80000000u) ? ~b : (b | 0x80000000u);
}

// round-to-nearest-even f32 -> bf16 bits (finite inputs only)
__device__ __forceinline__ unsigned int f2bf_bits(float f) {
  unsigned int u = __float_as_uint(f);
  unsigned int r = u + 0x7FFFu + ((u >> 16) & 1u);
  return r >> 16;
}

__global__ void k_zero_stats(float* __restrict__ ws) {
  int i = blockIdx.x * 256 + threadIdx.x;
  if (i < ZERO_FLOATS) ws[i] = 0.0f;
}

__global__ void k_init_out(unsigned int* __restrict__ out, int n) {
  int i = blockIdx.x * 256 + threadIdx.x;
  if (i < n) out[i] = 0u;
}

// K1: h1 = x@W1^T + b1 ; accumulate per-graph sum/sumsq/count (layer 1).
// Block = 256 threads over 256 nodes: thread = (channel-pair cp, node-group ng).
// norm_index is sorted -> graph runs are long; flush atomics only on change.
// Wave-uniformity: all 64 lanes of a wave share ng (tid>>6), so the
// g!=curg branch is wave-uniform.
__global__ __launch_bounds__(256) void k1_stats1(
    const float* __restrict__ x, const float* __restrict__ W1,
    const float* __restrict__ b1, const int* __restrict__ gidx,
    float* __restrict__ ws, int N) {
  __shared__ float xs[256 * 32];   // 32KB
  __shared__ int gs[256];
  const int tid = threadIdx.x;
  const int base = blockIdx.x * 256;
  const int nvalid = min(256, N - base);
  const float4* xg = (const float4*)(x + (size_t)base * 32);
  float4* xs4 = (float4*)xs;
  for (int i = tid; i < nvalid * 8; i += 256) xs4[i] = xg[i];
  for (int i = tid; i < nvalid; i += 256) gs[i] = gidx[base + i];
  __syncthreads();

  const int cp = tid & 63;     // channel pair -> channels 2cp, 2cp+1
  const int c0 = cp * 2;
  const int ng = tid >> 6;     // node group 0..3 (64 nodes each)
  float w0[32], w1r[32];
  #pragma unroll
  for (int k8 = 0; k8 < 8; ++k8) {
    ((float4*)w0)[k8]  = ((const float4*)(W1 + c0 * 32))[k8];
    ((float4*)w1r)[k8] = ((const float4*)(W1 + (c0 + 1) * 32))[k8];
  }
  const float bb0 = b1[c0], bb1 = b1[c0 + 1];
  float* sum1 = ws + OFF_SUM1;
  float* sq1  = ws + OFF_SQ1;
  float* cntp = ws + OFF_CNT;

  float s0 = 0.f, s1 = 0.f, q0 = 0.f, q1 = 0.f;
  int curg = -1, run = 0;
  const int nlo = ng * 64;
  const int nhi = min(nlo + 64, nvalid);
  for (int n = nlo; n < nhi; ++n) {
    int g = gs[n];
    if (g != curg) {
      if (curg >= 0) {
        atomicAdd(&sum1[curg * 128 + c0],     s0);
        atomicAdd(&sum1[curg * 128 + c0 + 1], s1);
        atomicAdd(&sq1[curg * 128 + c0],      q0);
        atomicAdd(&sq1[curg * 128 + c0 + 1],  q1);
        if (cp == 0) atomicAdd(&cntp[curg], (float)run);
      }
      curg = g; s0 = s1 = q0 = q1 = 0.f; run = 0;
    }
    const float* xr = xs + n * 32;
    float h0 = bb0, h1v = bb1;
    #pragma unroll
    for (int k8 = 0; k8 < 8; ++k8) {
      float4 xv = ((const float4*)xr)[k8];   // LDS broadcast read
      h0  = fmaf(xv.x, w0[k8*4+0], h0);  h0  = fmaf(xv.y, w0[k8*4+1], h0);
      h0  = fmaf(xv.z, w0[k8*4+2], h0);  h0  = fmaf(xv.w, w0[k8*4+3], h0);
      h1v = fmaf(xv.x, w1r[k8*4+0], h1v); h1v = fmaf(xv.y, w1r[k8*4+1], h1v);
      h1v = fmaf(xv.z, w1r[k8*4+2], h1v); h1v = fmaf(xv.w, w1r[k8*4+3], h1v);
    }
    s0 += h0;  q0 = fmaf(h0, h0, q0);
    s1 += h1v; q1 = fmaf(h1v, h1v, q1);
    ++run;
  }
  if (curg >= 0) {
    atomicAdd(&sum1[curg * 128 + c0],     s0);
    atomicAdd(&sum1[curg * 128 + c0 + 1], s1);
    atomicAdd(&sq1[curg * 128 + c0],      q0);
    atomicAdd(&sq1[curg * 128 + c0 + 1],  q1);
    if (cp == 0) atomicAdd(&cntp[curg], (float)run);
  }
}

// K2/K4: finalize stats -> a = rstd*gamma, c = beta - mean*a (affine fold)
__global__ void k2_fin(float* __restrict__ ws, const float* __restrict__ gamma,
                       const float* __restrict__ beta, int D, int off_sum,
                       int off_sq, int off_a, int off_c) {
  int i = blockIdx.x * 256 + threadIdx.x;
  if (i >= NGRAPH * D) return;
  int g = i / D, c = i % D;
  float cnt  = fmaxf(ws[OFF_CNT + g], 1.0f);
  float mean = ws[off_sum + i] / cnt;
  float ex2  = ws[off_sq + i] / cnt;
  float var  = fmaxf(ex2 - mean * mean, 0.0f);
  float a = rsqrtf(var + EPSV) * gamma[c];
  ws[off_a + i] = a;
  ws[off_c + i] = fmaf(-mean, a, beta[c]);
}

// K3 (templated): recompute h1, normalize+leaky (stats1), h2 = h1n@W2^T + b2.
// MODE 0: write h2 (bf16 packed) + accumulate layer-2 stats   [fused path]
// MODE 1: accumulate layer-2 stats only (no h2 buffer)        [fallback pass 1]
// MODE 2: apply norm2+leaky and scatter-max directly          [fallback pass 2]
template <int MODE>
__global__ __launch_bounds__(256) void k3_main(
    const float* __restrict__ x, const float* __restrict__ W1,
    const float* __restrict__ b1, const float* __restrict__ W2,
    const float* __restrict__ b2, const int* __restrict__ gidx,
    const int* __restrict__ sidx, float* __restrict__ ws,
    unsigned int* __restrict__ h2out, unsigned int* __restrict__ out,
    int N, int ntiles, int tpb) {
  __shared__ float w2t[128 * 64];  // W2 transposed [k][j], 32KB
  __shared__ float xs[64 * 32];    // 8KB
  __shared__ float h1s[64 * 128];  // 32KB
  __shared__ int gs[64];
  const int tid = threadIdx.x;
  for (int i = tid; i < 64 * 128; i += 256) {   // transpose once per block
    int j = i >> 7, k = i & 127;
    w2t[k * 64 + j] = W2[i];
  }
  // phase-B identity (wave-uniform half: tid>>7)
  const int c = tid & 127, half = tid >> 7;
  const float b1c = b1[c];
  float w1r[32];
  #pragma unroll
  for (int k8 = 0; k8 < 8; ++k8)
    ((float4*)w1r)[k8] = ((const float4*)(W1 + c * 32))[k8];
  // phase-C identity: 2 output channels x 8 nodes
  const int jp = tid & 31, nq = tid >> 5;
  const int j0 = jp * 2;
  const float b2j0 = b2[j0], b2j1 = b2[j0 + 1];
  float* sum2 = ws + OFF_SUM2;
  float* sq2  = ws + OFF_SQ2;
  float s0 = 0.f, s1 = 0.f, q0 = 0.f, q1 = 0.f;
  int curg2 = -1;
  float a1v = 0.f, c1v = 0.f; int curg1 = -1;

  const int t0 = blockIdx.x * tpb;
  const int t1 = min(t0 + tpb, ntiles);
  for (int t = t0; t < t1; ++t) {
    const int base = t * 64;
    const int nvalid = min(64, N - base);
    __syncthreads();   // prev phase C done before re-staging
    const float4* xg = (const float4*)(x + (size_t)base * 32);
    for (int i = tid; i < nvalid * 8; i += 256) ((float4*)xs)[i] = xg[i];
    if (tid < nvalid) gs[tid] = gidx[base + tid];
    __syncthreads();
    // phase B: h1n tile -> LDS
    {
      const int nb0 = half * 32;
      const int nb1 = min(nb0 + 32, nvalid);
      for (int n = nb0; n < nb1; ++n) {
        int g = gs[n];
        if (g != curg1) {
          curg1 = g;
          a1v = ws[OFF_A1 + g * 128 + c];
          c1v = ws[OFF_C1 + g * 128 + c];
        }
        float h = b1c;
        const float* xr = xs + n * 32;
        #pragma unroll
        for (int k8 = 0; k8 < 8; ++k8) {
          float4 xv = ((const float4*)xr)[k8];
          h = fmaf(xv.x, w1r[k8*4+0], h); h = fmaf(xv.y, w1r[k8*4+1], h);
          h = fmaf(xv.z, w1r[k8*4+2], h); h = fmaf(xv.w, w1r[k8*4+3], h);
        }
        float v = fmaf(h, a1v, c1v);
        v = v >= 0.f ? v : v * SLOPE;
        h1s[n * 128 + c] = v;
      }
    }
    __syncthreads();
    // phase C: h2 tile, K-tiled, W2 cols from w2t (2-way bank = free)
    float acc0[8], acc1[8];
    #pragma unroll
    for (int ni = 0; ni < 8; ++ni) { acc0[ni] = b2j0; acc1[ni] = b2j1; }
    #pragma unroll
    for (int kk = 0; kk < 128; kk += 32) {
      float wa[32], wb[32];
      #pragma unroll
      for (int k = 0; k < 32; ++k) {
        float2 wv = *(const float2*)(w2t + (kk + k) * 64 + j0);
        wa[k] = wv.x; wb[k] = wv.y;
      }
      #pragma unroll
      for (int ni = 0; ni < 8; ++ni) {
        const float* hr = h1s + (nq * 8 + ni) * 128 + kk;   // broadcast reads
        #pragma unroll
        for (int k8 = 0; k8 < 8; ++k8) {
          float4 hv = ((const float4*)hr)[k8];
          acc0[ni] = fmaf(hv.x, wa[k8*4+0], acc0[ni]);
          acc0[ni] = fmaf(hv.y, wa[k8*4+1], acc0[ni]);
          acc0[ni] = fmaf(hv.z, wa[k8*4+2], acc0[ni]);
          acc0[ni] = fmaf(hv.w, wa[k8*4+3], acc0[ni]);
          acc1[ni] = fmaf(hv.x, wb[k8*4+0], acc1[ni]);
          acc1[ni] = fmaf(hv.y, wb[k8*4+1], acc1[ni]);
          acc1[ni] = fmaf(hv.z, wb[k8*4+2], acc1[ni]);
          acc1[ni] = fmaf(hv.w, wb[k8*4+3], acc1[ni]);
        }
      }
    }
    // epilogue per mode
    #pragma unroll
    for (int ni = 0; ni < 8; ++ni) {
      int n = nq * 8 + ni;
      if (n >= nvalid) break;
      int g = gs[n];
      float v0 = acc0[ni], v1 = acc1[ni];
      if (MODE == 2) {
        int sp = sidx[base + n];
        float a0 = ws[OFF_A2 + g * 64 + j0];
        float a1 = ws[OFF_A2 + g * 64 + j0 + 1];
        float cc0 = ws[OFF_C2 + g * 64 + j0];
        float cc1 = ws[OFF_C2 + g * 64 + j0 + 1];
        float y0 = fmaf(v0, a0, cc0); y0 = y0 >= 0.f ? y0 : y0 * SLOPE;
        float y1 = fmaf(v1, a1, cc1); y1 = y1 >= 0.f ? y1 : y1 * SLOPE;
        unsigned int* o = out + (size_t)sp * 64 + j0;
        atomicMax(o + 0, enc_f32(y0));
        atomicMax(o + 1, enc_f32(y1));
      } else {
        if (g != curg2) {
          if (curg2 >= 0) {
            atomicAdd(&sum2[curg2 * 64 + j0],     s0);
            atomicAdd(&sum2[curg2 * 64 + j0 + 1], s1);
            atomicAdd(&sq2[curg2 * 64 + j0],      q0);
            atomicAdd(&sq2[curg2 * 64 + j0 + 1],  q1);
          }
          curg2 = g; s0 = s1 = q0 = q1 = 0.f;
        }
        s0 += v0; q0 = fmaf(v0, v0, q0);
        s1 += v1; q1 = fmaf(v1, v1, q1);
        if (MODE == 0)
          h2out[(size_t)(base + n) * 32 + jp] = (f2bf_bits(v1) << 16) | f2bf_bits(v0);
      }
    }
  }
  if (MODE != 2 && curg2 >= 0) {
    atomicAdd(&sum2[curg2 * 64 + j0],     s0);
    atomicAdd(&sum2[curg2 * 64 + j0 + 1], s1);
    atomicAdd(&sq2[curg2 * 64 + j0],      q0);
    atomicAdd(&sq2[curg2 * 64 + j0 + 1],  q1);
  }
}

// K5: normalize+leaky h2 (bf16), scatter-max (encoded uint atomicMax) into out.
__global__ __launch_bounds__(256) void k5_scatter(
    const unsigned int* __restrict__ h2, const int* __restrict__ gidx,
    const int* __restrict__ sidx, const float* __restrict__ ws,
    unsigned int* __restrict__ out, int N) {
  int t = blockIdx.x * 256 + threadIdx.x;
  int node = t >> 4;          // 16 threads per node, 4 channels each
  if (node >= N) return;
  int jq = t & 15, j = jq * 4;
  int g = gidx[node];
  int sp = sidx[node];
  float4 av = *(const float4*)(ws + OFF_A2 + g * 64 + j);
  float4 cv = *(const float4*)(ws + OFF_C2 + g * 64 + j);
  uint2 hv = *(const uint2*)(h2 + (size_t)node * 32 + jq * 2);
  float v0 = __uint_as_float(hv.x << 16);
  float v1 = __uint_as_float(hv.x & 0xFFFF0000u);
  float v2 = __uint_as_float(hv.y << 16);
  float v3 = __uint_as_float(hv.y & 0xFFFF0000u);
  v0 = fmaf(v0, av.x, cv.x); v0 = v0 >= 0.f ? v0 : v0 * SLOPE;
  v1 = fmaf(v1, av.y, cv.y); v1 = v1 >= 0.f ? v1 : v1 * SLOPE;
  v2 = fmaf(v2, av.z, cv.z); v2 = v2 >= 0.f ? v2 : v2 * SLOPE;
  v3 = fmaf(v3, av.w, cv.w); v3 = v3 >= 0.f ? v3 : v3 * SLOPE;
  unsigned int* o = out + (size_t)sp * 64 + j;
  atomicMax(o + 0, enc_f32(v0));
  atomicMax(o + 1, enc_f32(v1));
  atomicMax(o + 2, enc_f32(v2));
  atomicMax(o + 3, enc_f32(v3));
}

// K6: decode encoded uints in place; enc==0 means empty segment -> 0.0
__global__ void k6_decode(unsigned int* __restrict__ o, int n) {
  int i = blockIdx.x * 256 + threadIdx.x;
  if (i >= n) return;
  unsigned int e = o[i];
  float f;
  if (e == 0u) f = 0.0f;
  else if (e & 0x80000000u) f = __uint_as_float(e ^ 0x80000000u);
  else f = __uint_as_float(~e);
  ((float*)o)[i] = f;
}

extern "C" void kernel_launch(void* const* d_in, const int* in_sizes, int n_in,
                              void* d_out, int out_size, void* d_ws, size_t ws_size,
                              hipStream_t stream) {
  const float* x   = (const float*)d_in[0];
  const float* W1  = (const float*)d_in[1];
  const float* b1  = (const float*)d_in[2];
  const float* g1  = (const float*)d_in[3];
  const float* be1 = (const float*)d_in[4];
  const float* W2  = (const float*)d_in[5];
  const float* b2  = (const float*)d_in[6];
  const float* g2  = (const float*)d_in[7];
  const float* be2 = (const float*)d_in[8];
  const int* gidx  = (const int*)d_in[9];
  const int* sidx  = (const int*)d_in[10];
  const int N = in_sizes[9];
  float* ws = (float*)d_ws;
  unsigned int* h2 = (unsigned int*)((char*)d_ws + H2_BYTE_OFF);
  unsigned int* out_u = (unsigned int*)d_out;

  const size_t needed = (size_t)H2_BYTE_OFF + (size_t)N * 128;  // h2: N*32 dwords
  const bool fused = (ws_size >= needed);

  hipLaunchKernelGGL(k_zero_stats, dim3((ZERO_FLOATS + 255) / 256), dim3(256), 0, stream, ws);
  hipLaunchKernelGGL(k_init_out, dim3((out_size + 255) / 256), dim3(256), 0, stream,
                     out_u, out_size);
  hipLaunchKernelGGL(k1_stats1, dim3((N + 255) / 256), dim3(256), 0, stream,
                     x, W1, b1, gidx, ws, N);
  hipLaunchKernelGGL(k2_fin, dim3((NGRAPH * 128 + 255) / 256), dim3(256), 0, stream,
                     ws, g1, be1, 128, OFF_SUM1, OFF_SQ1, OFF_A1, OFF_C1);
  const int ntiles = (N + 63) / 64;
  const int tpb = 8;
  const dim3 k3grid((ntiles + tpb - 1) / tpb);
  if (fused) {
    k3_main<0><<<k3grid, 256, 0, stream>>>(x, W1, b1, W2, b2, gidx, sidx, ws,
                                           h2, out_u, N, ntiles, tpb);
    hipLaunchKernelGGL(k2_fin, dim3((NGRAPH * 64 + 255) / 256), dim3(256), 0, stream,
                       ws, g2, be2, 64, OFF_SUM2, OFF_SQ2, OFF_A2, OFF_C2);
    hipLaunchKernelGGL(k5_scatter, dim3((N * 16 + 255) / 256), dim3(256), 0, stream,
                       h2, gidx, sidx, ws, out_u, N);
  } else {
    // workspace too small for h2: stats pass, finalize, then recompute+scatter
    k3_main<1><<<k3grid, 256, 0, stream>>>(x, W1, b1, W2, b2, gidx, sidx, ws,
                                           (unsigned int*)d_ws, out_u, N, ntiles, tpb);
    hipLaunchKernelGGL(k2_fin, dim3((NGRAPH * 64 + 255) / 256), dim3(256), 0, stream,
                       ws, g2, be2, 64, OFF_SUM2, OFF_SQ2, OFF_A2, OFF_C2);
    k3_main<2><<<k3grid, 256, 0, stream>>>(x, W1, b1, W2, b2, gidx, sidx, ws,
                                           (unsigned int*)d_ws, out_u, N, ntiles, tpb);
  }
  hipLaunchKernelGGL(k6_decode, dim3((out_size + 255) / 256), dim3(256), 0, stream,
                     out_u, out_size);
}

// Round 4
// 1804.866 us; speedup vs baseline: 6.3020x; 6.3020x over previous
//
#include <hip/hip_runtime.h>
#include <hip/hip_bf16.h>
#include <stdint.h>

#define NGRAPH 16
#define EPSV 1e-5f
#define SLOPE 0.01f

// ws float-offset layout (stats area zeroed each launch)
#define OFF_SUM1 0        // [16][128]
#define OFF_SQ1  2048     // [16][128]
#define OFF_CNT  4096     // [16]
#define OFF_SUM2 4112     // [16][64]
#define OFF_SQ2  5136     // [16][64]
#define OFF_A1   6160     // [16][128]
#define OFF_C1   8208     // [16][128]
#define OFF_A2   10256    // [16][64]
#define OFF_C2   11280    // [16][64]
#define ZERO_FLOATS 6160  // sum1,sq1,cnt,sum2,sq2 must start at 0
#define H2_BYTE_OFF 65536 // bf16 h2 buffer lives here (N*32 dwords)

// monotone float->uint encoding: uint order == float order
__device__ __forceinline__ unsigned int enc_f32(float f) {
  unsigned int b = __float_as_uint(f);
  return (b & 0x80000000u) ? ~b : (b | 0x80000000u);
}

// round-to-nearest-even f32 -> bf16 bits (finite inputs only)
__device__ __forceinline__ unsigned int f2bf_bits(float f) {
  unsigned int u = __float_as_uint(f);
  unsigned int r = u + 0x7FFFu + ((u >> 16) & 1u);
  return r >> 16;
}

__global__ void k_zero_stats(float* __restrict__ ws) {
  int i = blockIdx.x * 256 + threadIdx.x;
  if (i < ZERO_FLOATS) ws[i] = 0.0f;
}

__global__ void k_init_out(unsigned int* __restrict__ out, int n) {
  int i = blockIdx.x * 256 + threadIdx.x;
  if (i < n) out[i] = 0u;
}

// K1: h1 = x@W1^T + b1 ; accumulate per-graph sum/sumsq/count (layer 1).
// Block = 256 threads over 256 nodes: thread = (channel-pair cp, node-group ng).
// norm_index is sorted -> graph runs are long; flush atomics only on change.
__global__ __launch_bounds__(256) void k1_stats1(
    const float* __restrict__ x, const float* __restrict__ W1,
    const float* __restrict__ b1, const int* __restrict__ gidx,
    float* __restrict__ ws, int N) {
  __shared__ float xs[256 * 32];   // 32KB
  __shared__ int gs[256];
  const int tid = threadIdx.x;
  const int base = blockIdx.x * 256;
  const int nvalid = min(256, N - base);
  const float4* xg = (const float4*)(x + (size_t)base * 32);
  float4* xs4 = (float4*)xs;
  for (int i = tid; i < nvalid * 8; i += 256) xs4[i] = xg[i];
  for (int i = tid; i < nvalid; i += 256) gs[i] = gidx[base + i];
  __syncthreads();

  const int cp = tid & 63;     // channel pair -> channels 2cp, 2cp+1
  const int c0 = cp * 2;
  const int ng = tid >> 6;     // node group 0..3 (64 nodes each)
  float w0[32], w1r[32];
  #pragma unroll
  for (int k8 = 0; k8 < 8; ++k8) {
    ((float4*)w0)[k8]  = ((const float4*)(W1 + c0 * 32))[k8];
    ((float4*)w1r)[k8] = ((const float4*)(W1 + (c0 + 1) * 32))[k8];
  }
  const float bb0 = b1[c0], bb1 = b1[c0 + 1];
  float* sum1 = ws + OFF_SUM1;
  float* sq1  = ws + OFF_SQ1;
  float* cntp = ws + OFF_CNT;

  float s0 = 0.f, s1 = 0.f, q0 = 0.f, q1 = 0.f;
  int curg = -1, run = 0;
  const int nlo = ng * 64;
  const int nhi = min(nlo + 64, nvalid);
  #pragma unroll 1
  for (int n = nlo; n < nhi; ++n) {
    int g = gs[n];
    if (g != curg) {
      if (curg >= 0) {
        atomicAdd(&sum1[curg * 128 + c0],     s0);
        atomicAdd(&sum1[curg * 128 + c0 + 1], s1);
        atomicAdd(&sq1[curg * 128 + c0],      q0);
        atomicAdd(&sq1[curg * 128 + c0 + 1],  q1);
        if (cp == 0) atomicAdd(&cntp[curg], (float)run);
      }
      curg = g; s0 = s1 = q0 = q1 = 0.f; run = 0;
    }
    const float* xr = xs + n * 32;
    float h0 = bb0, h1v = bb1;
    #pragma unroll
    for (int k8 = 0; k8 < 8; ++k8) {
      float4 xv = ((const float4*)xr)[k8];   // LDS broadcast read
      h0  = fmaf(xv.x, w0[k8*4+0], h0);  h0  = fmaf(xv.y, w0[k8*4+1], h0);
      h0  = fmaf(xv.z, w0[k8*4+2], h0);  h0  = fmaf(xv.w, w0[k8*4+3], h0);
      h1v = fmaf(xv.x, w1r[k8*4+0], h1v); h1v = fmaf(xv.y, w1r[k8*4+1], h1v);
      h1v = fmaf(xv.z, w1r[k8*4+2], h1v); h1v = fmaf(xv.w, w1r[k8*4+3], h1v);
    }
    s0 += h0;  q0 = fmaf(h0, h0, q0);
    s1 += h1v; q1 = fmaf(h1v, h1v, q1);
    ++run;
  }
  if (curg >= 0) {
    atomicAdd(&sum1[curg * 128 + c0],     s0);
    atomicAdd(&sum1[curg * 128 + c0 + 1], s1);
    atomicAdd(&sq1[curg * 128 + c0],      q0);
    atomicAdd(&sq1[curg * 128 + c0 + 1],  q1);
    if (cp == 0) atomicAdd(&cntp[curg], (float)run);
  }
}

// K2/K4: finalize stats -> a = rstd*gamma, c = beta - mean*a (affine fold)
__global__ void k2_fin(float* __restrict__ ws, const float* __restrict__ gamma,
                       const float* __restrict__ beta, int D, int off_sum,
                       int off_sq, int off_a, int off_c) {
  int i = blockIdx.x * 256 + threadIdx.x;
  if (i >= NGRAPH * D) return;
  int g = i / D, c = i % D;
  float cnt  = fmaxf(ws[OFF_CNT + g], 1.0f);
  float mean = ws[off_sum + i] / cnt;
  float ex2  = ws[off_sq + i] / cnt;
  float var  = fmaxf(ex2 - mean * mean, 0.0f);
  float a = rsqrtf(var + EPSV) * gamma[c];
  ws[off_a + i] = a;
  ws[off_c + i] = fmaf(-mean, a, beta[c]);
}

// K3 (templated): recompute h1, normalize+leaky (stats1), h2 = h1n@W2^T + b2.
// MODE 0: write h2 (bf16 packed) + accumulate layer-2 stats   [fused path]
// MODE 1: accumulate layer-2 stats only (no h2 buffer)        [fallback pass 1]
// MODE 2: apply norm2+leaky and scatter-max directly          [fallback pass 2]
// SPILL FIX (R4): phase-C weight cache shrunk 32->8 per channel and
// `#pragma unroll 1` on kk/tile loops. R3 fully unrolled kk with wa[32]+wb[32]
// -> ~256 live floats -> 26 GB scratch traffic (VGPR=256, VALUBusy 3.7%).
template <int MODE>
__global__ __launch_bounds__(256) void k3_main(
    const float* __restrict__ x, const float* __restrict__ W1,
    const float* __restrict__ b1, const float* __restrict__ W2,
    const float* __restrict__ b2, const int* __restrict__ gidx,
    const int* __restrict__ sidx, float* __restrict__ ws,
    unsigned int* __restrict__ h2out, unsigned int* __restrict__ out,
    int N, int ntiles, int tpb) {
  __shared__ float w2t[128 * 64];  // W2 transposed [k][j], 32KB
  __shared__ float xs[64 * 32];    // 8KB
  __shared__ float h1s[64 * 128];  // 32KB
  __shared__ int gs[64];
  const int tid = threadIdx.x;
  for (int i = tid; i < 64 * 128; i += 256) {   // transpose once per block
    int j = i >> 7, k = i & 127;
    w2t[k * 64 + j] = W2[i];
  }
  // phase-B identity (wave-uniform half: tid>>7)
  const int c = tid & 127, half = tid >> 7;
  const float b1c = b1[c];
  float w1r[32];
  #pragma unroll
  for (int k8 = 0; k8 < 8; ++k8)
    ((float4*)w1r)[k8] = ((const float4*)(W1 + c * 32))[k8];
  // phase-C identity: 2 output channels x 8 nodes
  const int jp = tid & 31, nq = tid >> 5;
  const int j0 = jp * 2;
  const float b2j0 = b2[j0], b2j1 = b2[j0 + 1];
  float* sum2 = ws + OFF_SUM2;
  float* sq2  = ws + OFF_SQ2;
  float s0 = 0.f, s1 = 0.f, q0 = 0.f, q1 = 0.f;
  int curg2 = -1;
  float a1v = 0.f, c1v = 0.f; int curg1 = -1;

  const int t0 = blockIdx.x * tpb;
  const int t1 = min(t0 + tpb, ntiles);
  #pragma unroll 1
  for (int t = t0; t < t1; ++t) {
    const int base = t * 64;
    const int nvalid = min(64, N - base);
    __syncthreads();   // prev phase C done before re-staging
    const float4* xg = (const float4*)(x + (size_t)base * 32);
    for (int i = tid; i < nvalid * 8; i += 256) ((float4*)xs)[i] = xg[i];
    if (tid < nvalid) gs[tid] = gidx[base + tid];
    __syncthreads();
    // phase B: h1n tile -> LDS
    {
      const int nb0 = half * 32;
      const int nb1 = min(nb0 + 32, nvalid);
      #pragma unroll 1
      for (int n = nb0; n < nb1; ++n) {
        int g = gs[n];
        if (g != curg1) {
          curg1 = g;
          a1v = ws[OFF_A1 + g * 128 + c];
          c1v = ws[OFF_C1 + g * 128 + c];
        }
        float h = b1c;
        const float* xr = xs + n * 32;
        #pragma unroll
        for (int k8 = 0; k8 < 8; ++k8) {
          float4 xv = ((const float4*)xr)[k8];
          h = fmaf(xv.x, w1r[k8*4+0], h); h = fmaf(xv.y, w1r[k8*4+1], h);
          h = fmaf(xv.z, w1r[k8*4+2], h); h = fmaf(xv.w, w1r[k8*4+3], h);
        }
        float v = fmaf(h, a1v, c1v);
        v = v >= 0.f ? v : v * SLOPE;
        h1s[n * 128 + c] = v;
      }
    }
    __syncthreads();
    // phase C: h2 tile. K-chunks of 8: weight cache = 16 regs, no spill.
    float acc0[8], acc1[8];
    #pragma unroll
    for (int ni = 0; ni < 8; ++ni) { acc0[ni] = b2j0; acc1[ni] = b2j1; }
    #pragma unroll 1
    for (int kk = 0; kk < 128; kk += 8) {
      float w2a[8], w2b[8];
      #pragma unroll
      for (int k = 0; k < 8; ++k) {
        float2 wv = *(const float2*)(w2t + (kk + k) * 64 + j0);  // 2-way = free
        w2a[k] = wv.x; w2b[k] = wv.y;
      }
      #pragma unroll
      for (int ni = 0; ni < 8; ++ni) {
        const float* hr = h1s + (nq * 8 + ni) * 128 + kk;   // broadcast reads
        float4 ha = ((const float4*)hr)[0];
        float4 hb = ((const float4*)hr)[1];
        acc0[ni] = fmaf(ha.x, w2a[0], acc0[ni]);
        acc0[ni] = fmaf(ha.y, w2a[1], acc0[ni]);
        acc0[ni] = fmaf(ha.z, w2a[2], acc0[ni]);
        acc0[ni] = fmaf(ha.w, w2a[3], acc0[ni]);
        acc0[ni] = fmaf(hb.x, w2a[4], acc0[ni]);
        acc0[ni] = fmaf(hb.y, w2a[5], acc0[ni]);
        acc0[ni] = fmaf(hb.z, w2a[6], acc0[ni]);
        acc0[ni] = fmaf(hb.w, w2a[7], acc0[ni]);
        acc1[ni] = fmaf(ha.x, w2b[0], acc1[ni]);
        acc1[ni] = fmaf(ha.y, w2b[1], acc1[ni]);
        acc1[ni] = fmaf(ha.z, w2b[2], acc1[ni]);
        acc1[ni] = fmaf(ha.w, w2b[3], acc1[ni]);
        acc1[ni] = fmaf(hb.x, w2b[4], acc1[ni]);
        acc1[ni] = fmaf(hb.y, w2b[5], acc1[ni]);
        acc1[ni] = fmaf(hb.z, w2b[6], acc1[ni]);
        acc1[ni] = fmaf(hb.w, w2b[7], acc1[ni]);
      }
    }
    // epilogue per mode
    #pragma unroll
    for (int ni = 0; ni < 8; ++ni) {
      int n = nq * 8 + ni;
      if (n >= nvalid) break;
      int g = gs[n];
      float v0 = acc0[ni], v1 = acc1[ni];
      if (MODE == 2) {
        int sp = sidx[base + n];
        float a0 = ws[OFF_A2 + g * 64 + j0];
        float a1 = ws[OFF_A2 + g * 64 + j0 + 1];
        float cc0 = ws[OFF_C2 + g * 64 + j0];
        float cc1 = ws[OFF_C2 + g * 64 + j0 + 1];
        float y0 = fmaf(v0, a0, cc0); y0 = y0 >= 0.f ? y0 : y0 * SLOPE;
        float y1 = fmaf(v1, a1, cc1); y1 = y1 >= 0.f ? y1 : y1 * SLOPE;
        unsigned int* o = out + (size_t)sp * 64 + j0;
        atomicMax(o + 0, enc_f32(y0));
        atomicMax(o + 1, enc_f32(y1));
      } else {
        if (g != curg2) {
          if (curg2 >= 0) {
            atomicAdd(&sum2[curg2 * 64 + j0],     s0);
            atomicAdd(&sum2[curg2 * 64 + j0 + 1], s1);
            atomicAdd(&sq2[curg2 * 64 + j0],      q0);
            atomicAdd(&sq2[curg2 * 64 + j0 + 1],  q1);
          }
          curg2 = g; s0 = s1 = q0 = q1 = 0.f;
        }
        s0 += v0; q0 = fmaf(v0, v0, q0);
        s1 += v1; q1 = fmaf(v1, v1, q1);
        if (MODE == 0)
          h2out[(size_t)(base + n) * 32 + jp] = (f2bf_bits(v1) << 16) | f2bf_bits(v0);
      }
    }
  }
  if (MODE != 2 && curg2 >= 0) {
    atomicAdd(&sum2[curg2 * 64 + j0],     s0);
    atomicAdd(&sum2[curg2 * 64 + j0 + 1], s1);
    atomicAdd(&sq2[curg2 * 64 + j0],      q0);
    atomicAdd(&sq2[curg2 * 64 + j0 + 1],  q1);
  }
}

// K5: normalize+leaky h2 (bf16), scatter-max (encoded uint atomicMax) into out.
__global__ __launch_bounds__(256) void k5_scatter(
    const unsigned int* __restrict__ h2, const int* __restrict__ gidx,
    const int* __restrict__ sidx, const float* __restrict__ ws,
    unsigned int* __restrict__ out, int N) {
  int t = blockIdx.x * 256 + threadIdx.x;
  int node = t >> 4;          // 16 threads per node, 4 channels each
  if (node >= N) return;
  int jq = t & 15, j = jq * 4;
  int g = gidx[node];
  int sp = sidx[node];
  float4 av = *(const float4*)(ws + OFF_A2 + g * 64 + j);
  float4 cv = *(const float4*)(ws + OFF_C2 + g * 64 + j);
  uint2 hv = *(const uint2*)(h2 + (size_t)node * 32 + jq * 2);
  float v0 = __uint_as_float(hv.x << 16);
  float v1 = __uint_as_float(hv.x & 0xFFFF0000u);
  float v2 = __uint_as_float(hv.y << 16);
  float v3 = __uint_as_float(hv.y & 0xFFFF0000u);
  v0 = fmaf(v0, av.x, cv.x); v0 = v0 >= 0.f ? v0 : v0 * SLOPE;
  v1 = fmaf(v1, av.y, cv.y); v1 = v1 >= 0.f ? v1 : v1 * SLOPE;
  v2 = fmaf(v2, av.z, cv.z); v2 = v2 >= 0.f ? v2 : v2 * SLOPE;
  v3 = fmaf(v3, av.w, cv.w); v3 = v3 >= 0.f ? v3 : v3 * SLOPE;
  unsigned int* o = out + (size_t)sp * 64 + j;
  atomicMax(o + 0, enc_f32(v0));
  atomicMax(o + 1, enc_f32(v1));
  atomicMax(o + 2, enc_f32(v2));
  atomicMax(o + 3, enc_f32(v3));
}

// K6: decode encoded uints in place; enc==0 means empty segment -> 0.0
__global__ void k6_decode(unsigned int* __restrict__ o, int n) {
  int i = blockIdx.x * 256 + threadIdx.x;
  if (i >= n) return;
  unsigned int e = o[i];
  float f;
  if (e == 0u) f = 0.0f;
  else if (e & 0x80000000u) f = __uint_as_float(e ^ 0x80000000u);
  else f = __uint_as_float(~e);
  ((float*)o)[i] = f;
}

extern "C" void kernel_launch(void* const* d_in, const int* in_sizes, int n_in,
                              void* d_out, int out_size, void* d_ws, size_t ws_size,
                              hipStream_t stream) {
  const float* x   = (const float*)d_in[0];
  const float* W1  = (const float*)d_in[1];
  const float* b1  = (const float*)d_in[2];
  const float* g1  = (const float*)d_in[3];
  const float* be1 = (const float*)d_in[4];
  const float* W2  = (const float*)d_in[5];
  const float* b2  = (const float*)d_in[6];
  const float* g2  = (const float*)d_in[7];
  const float* be2 = (const float*)d_in[8];
  const int* gidx  = (const int*)d_in[9];
  const int* sidx  = (const int*)d_in[10];
  const int N = in_sizes[9];
  float* ws = (float*)d_ws;
  unsigned int* h2 = (unsigned int*)((char*)d_ws + H2_BYTE_OFF);
  unsigned int* out_u = (unsigned int*)d_out;

  const size_t needed = (size_t)H2_BYTE_OFF + (size_t)N * 128;  // h2: N*32 dwords
  const bool fused = (ws_size >= needed);

  hipLaunchKernelGGL(k_zero_stats, dim3((ZERO_FLOATS + 255) / 256), dim3(256), 0, stream, ws);
  hipLaunchKernelGGL(k_init_out, dim3((out_size + 255) / 256), dim3(256), 0, stream,
                     out_u, out_size);
  hipLaunchKernelGGL(k1_stats1, dim3((N + 255) / 256), dim3(256), 0, stream,
                     x, W1, b1, gidx, ws, N);
  hipLaunchKernelGGL(k2_fin, dim3((NGRAPH * 128 + 255) / 256), dim3(256), 0, stream,
                     ws, g1, be1, 128, OFF_SUM1, OFF_SQ1, OFF_A1, OFF_C1);
  const int ntiles = (N + 63) / 64;
  const int tpb = 8;
  const dim3 k3grid((ntiles + tpb - 1) / tpb);
  if (fused) {
    k3_main<0><<<k3grid, 256, 0, stream>>>(x, W1, b1, W2, b2, gidx, sidx, ws,
                                           h2, out_u, N, ntiles, tpb);
    hipLaunchKernelGGL(k2_fin, dim3((NGRAPH * 64 + 255) / 256), dim3(256), 0, stream,
                       ws, g2, be2, 64, OFF_SUM2, OFF_SQ2, OFF_A2, OFF_C2);
    hipLaunchKernelGGL(k5_scatter, dim3((N * 16 + 255) / 256), dim3(256), 0, stream,
                       h2, gidx, sidx, ws, out_u, N);
  } else {
    // workspace too small for h2: stats pass, finalize, then recompute+scatter
    k3_main<1><<<k3grid, 256, 0, stream>>>(x, W1, b1, W2, b2, gidx, sidx, ws,
                                           (unsigned int*)d_ws, out_u, N, ntiles, tpb);
    hipLaunchKernelGGL(k2_fin, dim3((NGRAPH * 64 + 255) / 256), dim3(256), 0, stream,
                       ws, g2, be2, 64, OFF_SUM2, OFF_SQ2, OFF_A2, OFF_C2);
    k3_main<2><<<k3grid, 256, 0, stream>>>(x, W1, b1, W2, b2, gidx, sidx, ws,
                                           (unsigned int*)d_ws, out_u, N, ntiles, tpb);
  }
  hipLaunchKernelGGL(k6_decode, dim3((out_size + 255) / 256), dim3(256), 0, stream,
                     out_u, out_size);
}

// Round 5
// 1477.211 us; speedup vs baseline: 7.6999x; 1.2218x over previous
//
#include <hip/hip_runtime.h>
#include <hip/hip_bf16.h>
#include <stdint.h>

#define NGRAPH 16
#define EPSV 1e-5f
#define SLOPE 0.01f

// ---- ws float-offset layout ----
// small stats region (< 64 KB):
#define OFF_S1   0       // [16][32]  segment-sum of x (bf16-rounded)
#define OFF_CNT  512     // [16]
#define OFF_SUM2 528     // [16][64]
#define OFF_SQ2  1552    // [16][64]
#define ZERO_SMALL 2576
#define OFF_A1   2576    // [16][128]
#define OFF_C1   4624    // [16][128]
#define OFF_A2   6672    // [16][64]
#define OFF_C2   7696    // [16][64]   (end 8720 floats = 34.9 KB < 64 KB)
// M_g (16 x 32 x 32 f32 = 64 KB) lives at float offset 16384 (byte 65536),
// OVERLAPPING the h2 region: M is consumed by k2a before k3 writes h2.
#define OFF_M    16384
#define M_FLOATS 16384
#define H2_BYTE_OFF 65536   // bf16 h2 [N][64] — same offset as R3/R4 (proven fit)

typedef __attribute__((ext_vector_type(4))) float f32x4;
typedef __attribute__((ext_vector_type(8))) short short8v;

// monotone float->uint encoding: uint order == float order
__device__ __forceinline__ unsigned int enc_f32(float f) {
  unsigned int b = __float_as_uint(f);
  return (b & 0x80000000u) ? ~b : (b | 0x80000000u);
}
// RNE f32 -> bf16 bits (finite inputs)
__device__ __forceinline__ unsigned int f2bf_bits(float f) {
  unsigned int u = __float_as_uint(f);
  unsigned int r = u + 0x7FFFu + ((u >> 16) & 1u);
  return r >> 16;
}
// round f32 to the nearest-bf16 value, returned as f32 (matches f2bf_bits)
__device__ __forceinline__ float bfround(float f) {
  unsigned int u = __float_as_uint(f);
  unsigned int r = (u + 0x7FFFu + ((u >> 16) & 1u)) & 0xFFFF0000u;
  return __uint_as_float(r);
}

__global__ void k_zero_stats(float* __restrict__ ws) {
  int i = blockIdx.x * 256 + threadIdx.x;
  if (i < ZERO_SMALL) ws[i] = 0.0f;
  int j = i - ZERO_SMALL;
  if (j >= 0 && j < M_FLOATS) ws[OFF_M + j] = 0.0f;
}

__global__ void k_init_out(unsigned int* __restrict__ out, int n) {
  int i = blockIdx.x * 256 + threadIdx.x;
  if (i < n) out[i] = 0u;
}

// K1: per-graph second-moment M_g = sum x x^T, s_g = sum x, cnt — over
// bf16-ROUNDED x (so stats match the bf16 MFMA inputs in k3 exactly).
// Lane owns a 4x4 block of the 32x32 M: bi=l>>3 (rows), bj=l&7 (cols).
// Whole wave walks a contiguous node range; run-length flush on graph change
// (norm_index sorted -> rare, wave-uniform).
__global__ __launch_bounds__(256) void k1_mom(
    const float* __restrict__ x, const int* __restrict__ gidx,
    float* __restrict__ ws, int N) {
  const int tid = threadIdx.x;
  const int gw = blockIdx.x * 4 + (tid >> 6);
  const int l = tid & 63;
  const int bi = l >> 3, bj = l & 7;
  const bool diag = (bi == bj);
  const bool isL0 = (l == 0);
  const int nwaves = gridDim.x * 4;
  const int npw = (N + nwaves - 1) / nwaves;
  const int n0 = gw * npw;
  const int n1 = min(n0 + npw, N);

  float m00,m01,m02,m03,m10,m11,m12,m13,m20,m21,m22,m23,m30,m31,m32,m33;
  m00=m01=m02=m03=m10=m11=m12=m13=m20=m21=m22=m23=m30=m31=m32=m33=0.f;
  float sv0=0.f, sv1=0.f, sv2=0.f, sv3=0.f, cnt=0.f;
  int curg = -1;

  #pragma unroll 1
  for (int n = n0; n < n1; ++n) {
    int g = gidx[n];
    if (g != curg) {
      if (curg >= 0) {
        float* Mg = ws + OFF_M + curg * 1024 + bi * 4 * 32 + bj * 4;
        atomicAdd(Mg + 0*32 + 0, m00); atomicAdd(Mg + 0*32 + 1, m01);
        atomicAdd(Mg + 0*32 + 2, m02); atomicAdd(Mg + 0*32 + 3, m03);
        atomicAdd(Mg + 1*32 + 0, m10); atomicAdd(Mg + 1*32 + 1, m11);
        atomicAdd(Mg + 1*32 + 2, m12); atomicAdd(Mg + 1*32 + 3, m13);
        atomicAdd(Mg + 2*32 + 0, m20); atomicAdd(Mg + 2*32 + 1, m21);
        atomicAdd(Mg + 2*32 + 2, m22); atomicAdd(Mg + 2*32 + 3, m23);
        atomicAdd(Mg + 3*32 + 0, m30); atomicAdd(Mg + 3*32 + 1, m31);
        atomicAdd(Mg + 3*32 + 2, m32); atomicAdd(Mg + 3*32 + 3, m33);
        if (diag) {
          float* Sg = ws + OFF_S1 + curg * 32 + bi * 4;
          atomicAdd(Sg + 0, sv0); atomicAdd(Sg + 1, sv1);
          atomicAdd(Sg + 2, sv2); atomicAdd(Sg + 3, sv3);
        }
        if (isL0) atomicAdd(ws + OFF_CNT + curg, cnt);
      }
      curg = g;
      m00=m01=m02=m03=m10=m11=m12=m13=m20=m21=m22=m23=m30=m31=m32=m33=0.f;
      sv0=sv1=sv2=sv3=0.f; cnt=0.f;
    }
    const float* xr = x + (size_t)n * 32;
    float4 pi = *(const float4*)(xr + bi * 4);
    float4 pj = *(const float4*)(xr + bj * 4);
    float xi0 = bfround(pi.x), xi1 = bfround(pi.y), xi2 = bfround(pi.z), xi3 = bfround(pi.w);
    float xj0 = bfround(pj.x), xj1 = bfround(pj.y), xj2 = bfround(pj.z), xj3 = bfround(pj.w);
    m00 = fmaf(xi0,xj0,m00); m01 = fmaf(xi0,xj1,m01); m02 = fmaf(xi0,xj2,m02); m03 = fmaf(xi0,xj3,m03);
    m10 = fmaf(xi1,xj0,m10); m11 = fmaf(xi1,xj1,m11); m12 = fmaf(xi1,xj2,m12); m13 = fmaf(xi1,xj3,m13);
    m20 = fmaf(xi2,xj0,m20); m21 = fmaf(xi2,xj1,m21); m22 = fmaf(xi2,xj2,m22); m23 = fmaf(xi2,xj3,m23);
    m30 = fmaf(xi3,xj0,m30); m31 = fmaf(xi3,xj1,m31); m32 = fmaf(xi3,xj2,m32); m33 = fmaf(xi3,xj3,m33);
    if (diag) { sv0 += xi0; sv1 += xi1; sv2 += xi2; sv3 += xi3; }
    cnt += 1.f;
  }
  if (curg >= 0) {
    float* Mg = ws + OFF_M + curg * 1024 + bi * 4 * 32 + bj * 4;
    atomicAdd(Mg + 0*32 + 0, m00); atomicAdd(Mg + 0*32 + 1, m01);
    atomicAdd(Mg + 0*32 + 2, m02); atomicAdd(Mg + 0*32 + 3, m03);
    atomicAdd(Mg + 1*32 + 0, m10); atomicAdd(Mg + 1*32 + 1, m11);
    atomicAdd(Mg + 1*32 + 2, m12); atomicAdd(Mg + 1*32 + 3, m13);
    atomicAdd(Mg + 2*32 + 0, m20); atomicAdd(Mg + 2*32 + 1, m21);
    atomicAdd(Mg + 2*32 + 2, m22); atomicAdd(Mg + 2*32 + 3, m23);
    atomicAdd(Mg + 3*32 + 0, m30); atomicAdd(Mg + 3*32 + 1, m31);
    atomicAdd(Mg + 3*32 + 2, m32); atomicAdd(Mg + 3*32 + 3, m33);
    if (diag) {
      float* Sg = ws + OFF_S1 + curg * 32 + bi * 4;
      atomicAdd(Sg + 0, sv0); atomicAdd(Sg + 1, sv1);
      atomicAdd(Sg + 2, sv2); atomicAdd(Sg + 3, sv3);
    }
    if (isL0) atomicAdd(ws + OFF_CNT + curg, cnt);
  }
}

// K2a: layer-1 stats from moments. E[h^2] via quadratic form with
// bf16-rounded W1 (identical rounding to k3's MFMA fragments).
// Stores A1 = rstd*gamma, C1 = beta + A1*(b1 - mean)  (bias folded).
__global__ __launch_bounds__(128) void k2a_fin1(
    const float* __restrict__ W1, const float* __restrict__ b1,
    const float* __restrict__ g1, const float* __restrict__ be1,
    float* __restrict__ ws) {
  __shared__ float Ms[1024];
  __shared__ float ss[32];
  __shared__ float cs;
  const int g = blockIdx.x, c = threadIdx.x;
  for (int i = c; i < 1024; i += 128) Ms[i] = ws[OFF_M + g * 1024 + i];
  if (c < 32) ss[c] = ws[OFF_S1 + g * 32 + c];
  if (c == 0) cs = fmaxf(ws[OFF_CNT + g], 1.0f);
  __syncthreads();
  float w[32];
  #pragma unroll
  for (int k = 0; k < 32; ++k) w[k] = bfround(W1[c * 32 + k]);
  float dot = 0.f;
  #pragma unroll
  for (int k = 0; k < 32; ++k) dot = fmaf(w[k], ss[k], dot);
  float quad = 0.f;
  #pragma unroll 1
  for (int i = 0; i < 32; ++i) {
    const float* Mr = Ms + i * 32;
    float acc = 0.f;
    #pragma unroll
    for (int j = 0; j < 32; ++j) acc = fmaf(Mr[j], w[j], acc);
    quad = fmaf(w[i], acc, quad);
  }
  const float cnt = cs;
  const float bc = b1[c];
  const float mean = dot / cnt + bc;
  const float e2 = (quad + 2.f * bc * dot) / cnt + bc * bc;
  const float var = fmaxf(e2 - mean * mean, 0.0f);
  const float a = rsqrtf(var + EPSV) * g1[c];
  ws[OFF_A1 + g * 128 + c] = a;
  ws[OFF_C1 + g * 128 + c] = fmaf(a, bc - mean, be1[c]);
}

// K2: finalize layer-2 stats -> A2 = rstd*gamma, C2 = beta - mean*A2
__global__ void k2_fin(float* __restrict__ ws, const float* __restrict__ gamma,
                       const float* __restrict__ beta, int D, int off_sum,
                       int off_sq, int off_a, int off_c) {
  int i = blockIdx.x * 256 + threadIdx.x;
  if (i >= NGRAPH * D) return;
  int g = i / D, c = i % D;
  float cnt  = fmaxf(ws[OFF_CNT + g], 1.0f);
  float mean = ws[off_sum + i] / cnt;
  float ex2  = ws[off_sq + i] / cnt;
  float var  = fmaxf(ex2 - mean * mean, 0.0f);
  float a = rsqrtf(var + EPSV) * gamma[c];
  ws[off_a + i] = a;
  ws[off_c + i] = fmaf(-mean, a, beta[c]);
}

// K3: MFMA pipeline. Per wave, per 16-node tile:
//   layer1: h1 = xb @ W1b^T  — 8x mfma_f32_16x16x32_bf16 (K=32 in one shot)
//   normalize+leaky (A1/C1 staged in LDS) -> bf16 -> wave-private swizzled
//   LDS tile [16 rows][128 ch] (XOR byte^=(row&7)<<4: G4 fix for 256B rows)
//   layer2: h2 = h1n @ W2b^T — 16 mfma (4 ch-tiles x 4 K-tiles)
//   + b2, accumulate layer-2 stats (run-length atomics), store h2 bf16.
// A-frag: lane holds row l&15, k=(l>>4)*8+e. B-frag: col l&15, same k.
// C-frag (verified): col=l&15, row=(l>>4)*4+reg.
__global__ __launch_bounds__(256) void k3_mfma(
    const float* __restrict__ x, const float* __restrict__ W1,
    const float* __restrict__ W2, const float* __restrict__ b2,
    const int* __restrict__ gidx, float* __restrict__ ws,
    unsigned short* __restrict__ h2out, int N, int ntiles, int tpb) {
  __shared__ float a1s[2048];                 // A1 [16][128]
  __shared__ float c1s[2048];                 // C1 [16][128]
  __shared__ __align__(16) unsigned short h1t[4][2048];  // per-wave 16x128 bf16
  const int tid = threadIdx.x;
  const int wv = tid >> 6;      // wave in block
  const int l = tid & 63;
  const int ln = l & 15;        // row/col within fragment
  const int kq = l >> 4;        // k-group / C-row group

  for (int i = tid; i < 2048; i += 256) { a1s[i] = ws[OFF_A1 + i]; c1s[i] = ws[OFF_C1 + i]; }

  // persistent weight fragments (bf16-rounded, same rounding as stats path)
  short8v w1f[8];
  #pragma unroll
  for (int t = 0; t < 8; ++t) {
    const float* wr = W1 + (size_t)(t * 16 + ln) * 32 + kq * 8;
    float4 p = *(const float4*)wr, q = *(const float4*)(wr + 4);
    short8v f;
    f[0] = (short)f2bf_bits(p.x); f[1] = (short)f2bf_bits(p.y);
    f[2] = (short)f2bf_bits(p.z); f[3] = (short)f2bf_bits(p.w);
    f[4] = (short)f2bf_bits(q.x); f[5] = (short)f2bf_bits(q.y);
    f[6] = (short)f2bf_bits(q.z); f[7] = (short)f2bf_bits(q.w);
    w1f[t] = f;
  }
  short8v w2f[4][4];
  #pragma unroll
  for (int ct = 0; ct < 4; ++ct)
    #pragma unroll
    for (int kt = 0; kt < 4; ++kt) {
      const float* wr = W2 + (size_t)(ct * 16 + ln) * 128 + kt * 32 + kq * 8;
      float4 p = *(const float4*)wr, q = *(const float4*)(wr + 4);
      short8v f;
      f[0] = (short)f2bf_bits(p.x); f[1] = (short)f2bf_bits(p.y);
      f[2] = (short)f2bf_bits(p.z); f[3] = (short)f2bf_bits(p.w);
      f[4] = (short)f2bf_bits(q.x); f[5] = (short)f2bf_bits(q.y);
      f[6] = (short)f2bf_bits(q.z); f[7] = (short)f2bf_bits(q.w);
      w2f[ct][kt] = f;
    }
  float b2v[4];
  #pragma unroll
  for (int ct = 0; ct < 4; ++ct) b2v[ct] = b2[ct * 16 + ln];
  __syncthreads();

  unsigned short* myt = &h1t[wv][0];
  const f32x4 zero4 = {0.f, 0.f, 0.f, 0.f};
  float s2[4] = {0.f, 0.f, 0.f, 0.f}, q2[4] = {0.f, 0.f, 0.f, 0.f};
  int curg2 = -1;

  const int t0 = blockIdx.x * tpb;
  const int t1 = min(t0 + tpb, ntiles);
  #pragma unroll 1
  for (int tb = t0; tb < t1; tb += 4) {
    const int tile = tb + wv;
    const bool act = (tile < t1);
    int gg[4] = {0, 0, 0, 0};
    if (act) {
      const int base = tile * 16;
      // ---- layer 1 ----
      const int nodeA = min(base + ln, N - 1);
      const float* xr = x + (size_t)nodeA * 32 + kq * 8;
      float4 p = *(const float4*)xr, q = *(const float4*)(xr + 4);
      short8v af;
      af[0] = (short)f2bf_bits(p.x); af[1] = (short)f2bf_bits(p.y);
      af[2] = (short)f2bf_bits(p.z); af[3] = (short)f2bf_bits(p.w);
      af[4] = (short)f2bf_bits(q.x); af[5] = (short)f2bf_bits(q.y);
      af[6] = (short)f2bf_bits(q.z); af[7] = (short)f2bf_bits(q.w);
      f32x4 acc1[8];
      #pragma unroll
      for (int t = 0; t < 8; ++t)
        acc1[t] = __builtin_amdgcn_mfma_f32_16x16x32_bf16(af, w1f[t], zero4, 0, 0, 0);
      #pragma unroll
      for (int i = 0; i < 4; ++i)
        gg[i] = gidx[min(base + kq * 4 + i, N - 1)];
      // normalize + leaky -> swizzled LDS (bf16)
      #pragma unroll
      for (int t = 0; t < 8; ++t) {
        const int ct_ = t * 16 + ln;
        #pragma unroll
        for (int i = 0; i < 4; ++i) {
          const float a = a1s[gg[i] * 128 + ct_];
          const float cc = c1s[gg[i] * 128 + ct_];
          float v = fmaf(acc1[t][i], a, cc);
          v = v >= 0.f ? v : v * SLOPE;
          const int row = kq * 4 + i;
          const int byte = (row * 256 + ct_ * 2) ^ ((row & 7) << 4);
          *(unsigned short*)((char*)myt + byte) = (unsigned short)f2bf_bits(v);
        }
      }
    }
    __syncthreads();   // order LDS writes->reads (also block-uniform)
    if (act) {
      const int base = tile * 16;
      // ---- layer 2 ----
      short8v a2f[4];
      #pragma unroll
      for (int kt = 0; kt < 4; ++kt) {
        const int byte = (ln * 256 + kt * 64 + kq * 16) ^ ((ln & 7) << 4);
        a2f[kt] = *(const short8v*)((const char*)myt + byte);
      }
      f32x4 acc2[4];
      #pragma unroll
      for (int ct = 0; ct < 4; ++ct) {
        f32x4 a = zero4;
        #pragma unroll
        for (int kt = 0; kt < 4; ++kt)
          a = __builtin_amdgcn_mfma_f32_16x16x32_bf16(a2f[kt], w2f[ct][kt], a, 0, 0, 0);
        acc2[ct] = a;
      }
      // stats2 (run-length) + h2 store
      #pragma unroll
      for (int i = 0; i < 4; ++i) {
        const int node = base + kq * 4 + i;
        if (node >= N) break;
        const int g = gg[i];
        if (g != curg2) {
          if (curg2 >= 0) {
            #pragma unroll
            for (int ct = 0; ct < 4; ++ct) {
              atomicAdd(ws + OFF_SUM2 + curg2 * 64 + ct * 16 + ln, s2[ct]);
              atomicAdd(ws + OFF_SQ2  + curg2 * 64 + ct * 16 + ln, q2[ct]);
            }
          }
          curg2 = g;
          #pragma unroll
          for (int ct = 0; ct < 4; ++ct) { s2[ct] = 0.f; q2[ct] = 0.f; }
        }
        #pragma unroll
        for (int ct = 0; ct < 4; ++ct) {
          const float v2 = acc2[ct][i] + b2v[ct];
          s2[ct] += v2; q2[ct] = fmaf(v2, v2, q2[ct]);
          h2out[(size_t)node * 64 + ct * 16 + ln] = (unsigned short)f2bf_bits(v2);
        }
      }
    }
  }
  if (curg2 >= 0) {
    #pragma unroll
    for (int ct = 0; ct < 4; ++ct) {
      atomicAdd(ws + OFF_SUM2 + curg2 * 64 + ct * 16 + ln, s2[ct]);
      atomicAdd(ws + OFF_SQ2  + curg2 * 64 + ct * 16 + ln, q2[ct]);
    }
  }
}

// K5: normalize+leaky h2 (bf16), scatter-max (encoded uint atomicMax) into out.
__global__ __launch_bounds__(256) void k5_scatter(
    const unsigned int* __restrict__ h2, const int* __restrict__ gidx,
    const int* __restrict__ sidx, const float* __restrict__ ws,
    unsigned int* __restrict__ out, int N) {
  int t = blockIdx.x * 256 + threadIdx.x;
  int node = t >> 4;          // 16 threads per node, 4 channels each
  if (node >= N) return;
  int jq = t & 15, j = jq * 4;
  int g = gidx[node];
  int sp = sidx[node];
  float4 av = *(const float4*)(ws + OFF_A2 + g * 64 + j);
  float4 cv = *(const float4*)(ws + OFF_C2 + g * 64 + j);
  uint2 hv = *(const uint2*)(h2 + (size_t)node * 32 + jq * 2);
  float v0 = __uint_as_float(hv.x << 16);
  float v1 = __uint_as_float(hv.x & 0xFFFF0000u);
  float v2 = __uint_as_float(hv.y << 16);
  float v3 = __uint_as_float(hv.y & 0xFFFF0000u);
  v0 = fmaf(v0, av.x, cv.x); v0 = v0 >= 0.f ? v0 : v0 * SLOPE;
  v1 = fmaf(v1, av.y, cv.y); v1 = v1 >= 0.f ? v1 : v1 * SLOPE;
  v2 = fmaf(v2, av.z, cv.z); v2 = v2 >= 0.f ? v2 : v2 * SLOPE;
  v3 = fmaf(v3, av.w, cv.w); v3 = v3 >= 0.f ? v3 : v3 * SLOPE;
  unsigned int* o = out + (size_t)sp * 64 + j;
  atomicMax(o + 0, enc_f32(v0));
  atomicMax(o + 1, enc_f32(v1));
  atomicMax(o + 2, enc_f32(v2));
  atomicMax(o + 3, enc_f32(v3));
}

// K6: decode encoded uints in place; enc==0 means empty segment -> 0.0
__global__ void k6_decode(unsigned int* __restrict__ o, int n) {
  int i = blockIdx.x * 256 + threadIdx.x;
  if (i >= n) return;
  unsigned int e = o[i];
  float f;
  if (e == 0u) f = 0.0f;
  else if (e & 0x80000000u) f = __uint_as_float(e ^ 0x80000000u);
  else f = __uint_as_float(~e);
  ((float*)o)[i] = f;
}

extern "C" void kernel_launch(void* const* d_in, const int* in_sizes, int n_in,
                              void* d_out, int out_size, void* d_ws, size_t ws_size,
                              hipStream_t stream) {
  const float* x   = (const float*)d_in[0];
  const float* W1  = (const float*)d_in[1];
  const float* b1  = (const float*)d_in[2];
  const float* g1  = (const float*)d_in[3];
  const float* be1 = (const float*)d_in[4];
  const float* W2  = (const float*)d_in[5];
  const float* b2  = (const float*)d_in[6];
  const float* g2  = (const float*)d_in[7];
  const float* be2 = (const float*)d_in[8];
  const int* gidx  = (const int*)d_in[9];
  const int* sidx  = (const int*)d_in[10];
  const int N = in_sizes[9];
  float* ws = (float*)d_ws;
  unsigned short* h2 = (unsigned short*)((char*)d_ws + H2_BYTE_OFF);
  unsigned int* out_u = (unsigned int*)d_out;

  const int zthreads = ZERO_SMALL + M_FLOATS;
  hipLaunchKernelGGL(k_zero_stats, dim3((zthreads + 255) / 256), dim3(256), 0, stream, ws);
  hipLaunchKernelGGL(k_init_out, dim3((out_size + 255) / 256), dim3(256), 0, stream,
                     out_u, out_size);
  hipLaunchKernelGGL(k1_mom, dim3(1024), dim3(256), 0, stream, x, gidx, ws, N);
  hipLaunchKernelGGL(k2a_fin1, dim3(NGRAPH), dim3(128), 0, stream, W1, b1, g1, be1, ws);
  const int ntiles = (N + 15) / 16;                 // N = 1e6 -> 62500 (div by 16)
  const int tpb = (ntiles + 1023) / 1024;           // tiles per block (62)
  const int k3blocks = (ntiles + tpb - 1) / tpb;
  hipLaunchKernelGGL(k3_mfma, dim3(k3blocks), dim3(256), 0, stream,
                     x, W1, W2, b2, gidx, ws, h2, N, ntiles, tpb);
  hipLaunchKernelGGL(k2_fin, dim3((NGRAPH * 64 + 255) / 256), dim3(256), 0, stream,
                     ws, g2, be2, 64, OFF_SUM2, OFF_SQ2, OFF_A2, OFF_C2);
  hipLaunchKernelGGL(k5_scatter, dim3((N * 16 + 255) / 256), dim3(256), 0, stream,
                     (const unsigned int*)h2, gidx, sidx, ws, out_u, N);
  hipLaunchKernelGGL(k6_decode, dim3((out_size + 255) / 256), dim3(256), 0, stream,
                     out_u, out_size);
}

// Round 6
// 1133.069 us; speedup vs baseline: 10.0385x; 1.3037x over previous
//
#include <hip/hip_runtime.h>
#include <hip/hip_bf16.h>
#include <stdint.h>

#define NGRAPH 16
#define EPSV 1e-5f
#define SLOPE 0.01f

// ---- ws float-offset layout ----
#define OFF_S1   0       // [16][32]  segment-sum of x (bf16-rounded)
#define OFF_CNT  512     // [16]
#define OFF_SUM2 528     // [16][64]
#define OFF_SQ2  1552    // [16][64]
#define ZERO_SMALL 2576
#define OFF_A1   2576    // [16][128]
#define OFF_C1   4624    // [16][128]
#define OFF_A2   6672    // [16][64]
#define OFF_C2   7696    // [16][64]
// M_g (16 x 32 x 32 f32 = 64 KB) at byte 65536, OVERLAPPING h2 (consumed
// by k2a before k3 writes h2).
#define OFF_M    16384
#define M_FLOATS 16384
#define H2_BYTE_OFF 65536   // bf16 h2 [N][64]

typedef __attribute__((ext_vector_type(4))) float f32x4;
typedef __attribute__((ext_vector_type(8))) short short8v;

__device__ __forceinline__ unsigned int enc_f32(float f) {
  unsigned int b = __float_as_uint(f);
  return (b & 0x80000000u) ? ~b : (b | 0x80000000u);
}
__device__ __forceinline__ unsigned int f2bf_bits(float f) {
  unsigned int u = __float_as_uint(f);
  unsigned int r = u + 0x7FFFu + ((u >> 16) & 1u);
  return r >> 16;
}
__device__ __forceinline__ float bfround(float f) {
  unsigned int u = __float_as_uint(f);
  unsigned int r = (u + 0x7FFFu + ((u >> 16) & 1u)) & 0xFFFF0000u;
  return __uint_as_float(r);
}

__global__ void k_zero_stats(float* __restrict__ ws) {
  int i = blockIdx.x * 256 + threadIdx.x;
  if (i < ZERO_SMALL) ws[i] = 0.0f;
  int j = i - ZERO_SMALL;
  if (j >= 0 && j < M_FLOATS) ws[OFF_M + j] = 0.0f;
}

__global__ void k_zero_ints(int* __restrict__ p, int n) {
  int i = blockIdx.x * 256 + threadIdx.x;
  if (i < n) p[i] = 0;
}

__global__ void k_init_out(unsigned int* __restrict__ out, int n) {
  int i = blockIdx.x * 256 + threadIdx.x;
  if (i < n) out[i] = 0u;
}

// K1: per-graph second moments M_g = sum x x^T, s_g, cnt over bf16-rounded x.
__global__ __launch_bounds__(256) void k1_mom(
    const float* __restrict__ x, const int* __restrict__ gidx,
    float* __restrict__ ws, int N) {
  const int tid = threadIdx.x;
  const int gw = blockIdx.x * 4 + (tid >> 6);
  const int l = tid & 63;
  const int bi = l >> 3, bj = l & 7;
  const bool diag = (bi == bj);
  const bool isL0 = (l == 0);
  const int nwaves = gridDim.x * 4;
  const int npw = (N + nwaves - 1) / nwaves;
  const int n0 = gw * npw;
  const int n1 = min(n0 + npw, N);

  float m00,m01,m02,m03,m10,m11,m12,m13,m20,m21,m22,m23,m30,m31,m32,m33;
  m00=m01=m02=m03=m10=m11=m12=m13=m20=m21=m22=m23=m30=m31=m32=m33=0.f;
  float sv0=0.f, sv1=0.f, sv2=0.f, sv3=0.f, cnt=0.f;
  int curg = -1;

  #pragma unroll 1
  for (int n = n0; n < n1; ++n) {
    int g = gidx[n];
    if (g != curg) {
      if (curg >= 0) {
        float* Mg = ws + OFF_M + curg * 1024 + bi * 4 * 32 + bj * 4;
        atomicAdd(Mg + 0*32 + 0, m00); atomicAdd(Mg + 0*32 + 1, m01);
        atomicAdd(Mg + 0*32 + 2, m02); atomicAdd(Mg + 0*32 + 3, m03);
        atomicAdd(Mg + 1*32 + 0, m10); atomicAdd(Mg + 1*32 + 1, m11);
        atomicAdd(Mg + 1*32 + 2, m12); atomicAdd(Mg + 1*32 + 3, m13);
        atomicAdd(Mg + 2*32 + 0, m20); atomicAdd(Mg + 2*32 + 1, m21);
        atomicAdd(Mg + 2*32 + 2, m22); atomicAdd(Mg + 2*32 + 3, m23);
        atomicAdd(Mg + 3*32 + 0, m30); atomicAdd(Mg + 3*32 + 1, m31);
        atomicAdd(Mg + 3*32 + 2, m32); atomicAdd(Mg + 3*32 + 3, m33);
        if (diag) {
          float* Sg = ws + OFF_S1 + curg * 32 + bi * 4;
          atomicAdd(Sg + 0, sv0); atomicAdd(Sg + 1, sv1);
          atomicAdd(Sg + 2, sv2); atomicAdd(Sg + 3, sv3);
        }
        if (isL0) atomicAdd(ws + OFF_CNT + curg, cnt);
      }
      curg = g;
      m00=m01=m02=m03=m10=m11=m12=m13=m20=m21=m22=m23=m30=m31=m32=m33=0.f;
      sv0=sv1=sv2=sv3=0.f; cnt=0.f;
    }
    const float* xr = x + (size_t)n * 32;
    float4 pi = *(const float4*)(xr + bi * 4);
    float4 pj = *(const float4*)(xr + bj * 4);
    float xi0 = bfround(pi.x), xi1 = bfround(pi.y), xi2 = bfround(pi.z), xi3 = bfround(pi.w);
    float xj0 = bfround(pj.x), xj1 = bfround(pj.y), xj2 = bfround(pj.z), xj3 = bfround(pj.w);
    m00 = fmaf(xi0,xj0,m00); m01 = fmaf(xi0,xj1,m01); m02 = fmaf(xi0,xj2,m02); m03 = fmaf(xi0,xj3,m03);
    m10 = fmaf(xi1,xj0,m10); m11 = fmaf(xi1,xj1,m11); m12 = fmaf(xi1,xj2,m12); m13 = fmaf(xi1,xj3,m13);
    m20 = fmaf(xi2,xj0,m20); m21 = fmaf(xi2,xj1,m21); m22 = fmaf(xi2,xj2,m22); m23 = fmaf(xi2,xj3,m23);
    m30 = fmaf(xi3,xj0,m30); m31 = fmaf(xi3,xj1,m31); m32 = fmaf(xi3,xj2,m32); m33 = fmaf(xi3,xj3,m33);
    if (diag) { sv0 += xi0; sv1 += xi1; sv2 += xi2; sv3 += xi3; }
    cnt += 1.f;
  }
  if (curg >= 0) {
    float* Mg = ws + OFF_M + curg * 1024 + bi * 4 * 32 + bj * 4;
    atomicAdd(Mg + 0*32 + 0, m00); atomicAdd(Mg + 0*32 + 1, m01);
    atomicAdd(Mg + 0*32 + 2, m02); atomicAdd(Mg + 0*32 + 3, m03);
    atomicAdd(Mg + 1*32 + 0, m10); atomicAdd(Mg + 1*32 + 1, m11);
    atomicAdd(Mg + 1*32 + 2, m12); atomicAdd(Mg + 1*32 + 3, m13);
    atomicAdd(Mg + 2*32 + 0, m20); atomicAdd(Mg + 2*32 + 1, m21);
    atomicAdd(Mg + 2*32 + 2, m22); atomicAdd(Mg + 2*32 + 3, m23);
    atomicAdd(Mg + 3*32 + 0, m30); atomicAdd(Mg + 3*32 + 1, m31);
    atomicAdd(Mg + 3*32 + 2, m32); atomicAdd(Mg + 3*32 + 3, m33);
    if (diag) {
      float* Sg = ws + OFF_S1 + curg * 32 + bi * 4;
      atomicAdd(Sg + 0, sv0); atomicAdd(Sg + 1, sv1);
      atomicAdd(Sg + 2, sv2); atomicAdd(Sg + 3, sv3);
    }
    if (isL0) atomicAdd(ws + OFF_CNT + curg, cnt);
  }
}

// K2a: layer-1 stats from moments (rounding identical to k3's MFMA inputs).
__global__ __launch_bounds__(128) void k2a_fin1(
    const float* __restrict__ W1, const float* __restrict__ b1,
    const float* __restrict__ g1, const float* __restrict__ be1,
    float* __restrict__ ws) {
  __shared__ float Ms[1024];
  __shared__ float ss[32];
  __shared__ float cs;
  const int g = blockIdx.x, c = threadIdx.x;
  for (int i = c; i < 1024; i += 128) Ms[i] = ws[OFF_M + g * 1024 + i];
  if (c < 32) ss[c] = ws[OFF_S1 + g * 32 + c];
  if (c == 0) cs = fmaxf(ws[OFF_CNT + g], 1.0f);
  __syncthreads();
  float w[32];
  #pragma unroll
  for (int k = 0; k < 32; ++k) w[k] = bfround(W1[c * 32 + k]);
  float dot = 0.f;
  #pragma unroll
  for (int k = 0; k < 32; ++k) dot = fmaf(w[k], ss[k], dot);
  float quad = 0.f;
  #pragma unroll 1
  for (int i = 0; i < 32; ++i) {
    const float* Mr = Ms + i * 32;
    float acc = 0.f;
    #pragma unroll
    for (int j = 0; j < 32; ++j) acc = fmaf(Mr[j], w[j], acc);
    quad = fmaf(w[i], acc, quad);
  }
  const float cnt = cs;
  const float bc = b1[c];
  const float mean = dot / cnt + bc;
  const float e2 = (quad + 2.f * bc * dot) / cnt + bc * bc;
  const float var = fmaxf(e2 - mean * mean, 0.0f);
  const float a = rsqrtf(var + EPSV) * g1[c];
  ws[OFF_A1 + g * 128 + c] = a;
  ws[OFF_C1 + g * 128 + c] = fmaf(a, bc - mean, be1[c]);
}

// K2: finalize layer-2 stats -> A2 = rstd*gamma, C2 = beta - mean*A2
__global__ void k2_fin(float* __restrict__ ws, const float* __restrict__ gamma,
                       const float* __restrict__ beta, int D, int off_sum,
                       int off_sq, int off_a, int off_c) {
  int i = blockIdx.x * 256 + threadIdx.x;
  if (i >= NGRAPH * D) return;
  int g = i / D, c = i % D;
  float cnt  = fmaxf(ws[OFF_CNT + g], 1.0f);
  float mean = ws[off_sum + i] / cnt;
  float ex2  = ws[off_sq + i] / cnt;
  float var  = fmaxf(ex2 - mean * mean, 0.0f);
  float a = rsqrtf(var + EPSV) * gamma[c];
  ws[off_a + i] = a;
  ws[off_c + i] = fmaf(-mean, a, beta[c]);
}

// K3: MFMA pipeline (unchanged from R5 — passed at absmax 0.031).
__global__ __launch_bounds__(256) void k3_mfma(
    const float* __restrict__ x, const float* __restrict__ W1,
    const float* __restrict__ W2, const float* __restrict__ b2,
    const int* __restrict__ gidx, float* __restrict__ ws,
    unsigned short* __restrict__ h2out, int N, int ntiles, int tpb) {
  __shared__ float a1s[2048];
  __shared__ float c1s[2048];
  __shared__ __align__(16) unsigned short h1t[4][2048];
  const int tid = threadIdx.x;
  const int wv = tid >> 6;
  const int l = tid & 63;
  const int ln = l & 15;
  const int kq = l >> 4;

  for (int i = tid; i < 2048; i += 256) { a1s[i] = ws[OFF_A1 + i]; c1s[i] = ws[OFF_C1 + i]; }

  short8v w1f[8];
  #pragma unroll
  for (int t = 0; t < 8; ++t) {
    const float* wr = W1 + (size_t)(t * 16 + ln) * 32 + kq * 8;
    float4 p = *(const float4*)wr, q = *(const float4*)(wr + 4);
    short8v f;
    f[0] = (short)f2bf_bits(p.x); f[1] = (short)f2bf_bits(p.y);
    f[2] = (short)f2bf_bits(p.z); f[3] = (short)f2bf_bits(p.w);
    f[4] = (short)f2bf_bits(q.x); f[5] = (short)f2bf_bits(q.y);
    f[6] = (short)f2bf_bits(q.z); f[7] = (short)f2bf_bits(q.w);
    w1f[t] = f;
  }
  short8v w2f[4][4];
  #pragma unroll
  for (int ct = 0; ct < 4; ++ct)
    #pragma unroll
    for (int kt = 0; kt < 4; ++kt) {
      const float* wr = W2 + (size_t)(ct * 16 + ln) * 128 + kt * 32 + kq * 8;
      float4 p = *(const float4*)wr, q = *(const float4*)(wr + 4);
      short8v f;
      f[0] = (short)f2bf_bits(p.x); f[1] = (short)f2bf_bits(p.y);
      f[2] = (short)f2bf_bits(p.z); f[3] = (short)f2bf_bits(p.w);
      f[4] = (short)f2bf_bits(q.x); f[5] = (short)f2bf_bits(q.y);
      f[6] = (short)f2bf_bits(q.z); f[7] = (short)f2bf_bits(q.w);
      w2f[ct][kt] = f;
    }
  float b2v[4];
  #pragma unroll
  for (int ct = 0; ct < 4; ++ct) b2v[ct] = b2[ct * 16 + ln];
  __syncthreads();

  unsigned short* myt = &h1t[wv][0];
  const f32x4 zero4 = {0.f, 0.f, 0.f, 0.f};
  float s2[4] = {0.f, 0.f, 0.f, 0.f}, q2[4] = {0.f, 0.f, 0.f, 0.f};
  int curg2 = -1;

  const int t0 = blockIdx.x * tpb;
  const int t1 = min(t0 + tpb, ntiles);
  #pragma unroll 1
  for (int tb = t0; tb < t1; tb += 4) {
    const int tile = tb + wv;
    const bool act = (tile < t1);
    int gg[4] = {0, 0, 0, 0};
    if (act) {
      const int base = tile * 16;
      const int nodeA = min(base + ln, N - 1);
      const float* xr = x + (size_t)nodeA * 32 + kq * 8;
      float4 p = *(const float4*)xr, q = *(const float4*)(xr + 4);
      short8v af;
      af[0] = (short)f2bf_bits(p.x); af[1] = (short)f2bf_bits(p.y);
      af[2] = (short)f2bf_bits(p.z); af[3] = (short)f2bf_bits(p.w);
      af[4] = (short)f2bf_bits(q.x); af[5] = (short)f2bf_bits(q.y);
      af[6] = (short)f2bf_bits(q.z); af[7] = (short)f2bf_bits(q.w);
      f32x4 acc1[8];
      #pragma unroll
      for (int t = 0; t < 8; ++t)
        acc1[t] = __builtin_amdgcn_mfma_f32_16x16x32_bf16(af, w1f[t], zero4, 0, 0, 0);
      #pragma unroll
      for (int i = 0; i < 4; ++i)
        gg[i] = gidx[min(base + kq * 4 + i, N - 1)];
      #pragma unroll
      for (int t = 0; t < 8; ++t) {
        const int ct_ = t * 16 + ln;
        #pragma unroll
        for (int i = 0; i < 4; ++i) {
          const float a = a1s[gg[i] * 128 + ct_];
          const float cc = c1s[gg[i] * 128 + ct_];
          float v = fmaf(acc1[t][i], a, cc);
          v = v >= 0.f ? v : v * SLOPE;
          const int row = kq * 4 + i;
          const int byte = (row * 256 + ct_ * 2) ^ ((row & 7) << 4);
          *(unsigned short*)((char*)myt + byte) = (unsigned short)f2bf_bits(v);
        }
      }
    }
    __syncthreads();
    if (act) {
      const int base = tile * 16;
      short8v a2f[4];
      #pragma unroll
      for (int kt = 0; kt < 4; ++kt) {
        const int byte = (ln * 256 + kt * 64 + kq * 16) ^ ((ln & 7) << 4);
        a2f[kt] = *(const short8v*)((const char*)myt + byte);
      }
      f32x4 acc2[4];
      #pragma unroll
      for (int ct = 0; ct < 4; ++ct) {
        f32x4 a = zero4;
        #pragma unroll
        for (int kt = 0; kt < 4; ++kt)
          a = __builtin_amdgcn_mfma_f32_16x16x32_bf16(a2f[kt], w2f[ct][kt], a, 0, 0, 0);
        acc2[ct] = a;
      }
      #pragma unroll
      for (int i = 0; i < 4; ++i) {
        const int node = base + kq * 4 + i;
        if (node >= N) break;
        const int g = gg[i];
        if (g != curg2) {
          if (curg2 >= 0) {
            #pragma unroll
            for (int ct = 0; ct < 4; ++ct) {
              atomicAdd(ws + OFF_SUM2 + curg2 * 64 + ct * 16 + ln, s2[ct]);
              atomicAdd(ws + OFF_SQ2  + curg2 * 64 + ct * 16 + ln, q2[ct]);
            }
          }
          curg2 = g;
          #pragma unroll
          for (int ct = 0; ct < 4; ++ct) { s2[ct] = 0.f; q2[ct] = 0.f; }
        }
        #pragma unroll
        for (int ct = 0; ct < 4; ++ct) {
          const float v2 = acc2[ct][i] + b2v[ct];
          s2[ct] += v2; q2[ct] = fmaf(v2, v2, q2[ct]);
          h2out[(size_t)node * 64 + ct * 16 + ln] = (unsigned short)f2bf_bits(v2);
        }
      }
    }
  }
  if (curg2 >= 0) {
    #pragma unroll
    for (int ct = 0; ct < 4; ++ct) {
      atomicAdd(ws + OFF_SUM2 + curg2 * 64 + ct * 16 + ln, s2[ct]);
      atomicAdd(ws + OFF_SQ2  + curg2 * 64 + ct * 16 + ln, q2[ct]);
    }
  }
}

// ---- R6: scatter-max via counting-sort inverse index (no out atomics) ----
// k5a: histogram of super_index
__global__ void k5a_hist(const int* __restrict__ sidx, int* __restrict__ hist, int N) {
  int n = blockIdx.x * 256 + threadIdx.x;
  if (n < N) atomicAdd(&hist[sidx[n]], 1);
}

// k5b: single-workgroup exclusive scan -> offsets[M+1] and cursor[M]
__global__ __launch_bounds__(256) void k5b_scan(
    const int* __restrict__ hist, int* __restrict__ offsets,
    int* __restrict__ cursor, int M, int N) {
  __shared__ int part[256];
  const int tid = threadIdx.x;
  const int chunk = (M + 255) / 256;
  const int lo = min(tid * chunk, M), hi = min(lo + chunk, M);
  int s = 0;
  for (int i = lo; i < hi; ++i) s += hist[i];
  part[tid] = s;
  __syncthreads();
  if (tid == 0) {
    int run = 0;
    for (int i = 0; i < 256; ++i) { int v = part[i]; part[i] = run; run += v; }
  }
  __syncthreads();
  int run = part[tid];
  for (int i = lo; i < hi; ++i) {
    int v = hist[i];
    offsets[i] = run; cursor[i] = run; run += v;
  }
  if (tid == 255) offsets[M] = N;
}

// k5c: scatter node ids into perm (segment-grouped, unordered within segment)
__global__ void k5c_perm(const int* __restrict__ sidx, int* __restrict__ cursor,
                         int* __restrict__ perm, int N) {
  int n = blockIdx.x * 256 + threadIdx.x;
  if (n >= N) return;
  int sp = sidx[n];
  int pos = atomicAdd(&cursor[sp], 1);
  perm[pos] = n;
}

// k5d: one wave per segment, lane = channel. normalize+leaky+max, plain store.
__global__ __launch_bounds__(256) void k5d_gather(
    const unsigned short* __restrict__ h2, const int* __restrict__ perm,
    const int* __restrict__ offsets, const int* __restrict__ gidx,
    const float* __restrict__ ws, float* __restrict__ out, int M) {
  __shared__ float a2s[1024], c2s[1024];
  const int tid = threadIdx.x;
  for (int i = tid; i < 1024; i += 256) { a2s[i] = ws[OFF_A2 + i]; c2s[i] = ws[OFF_C2 + i]; }
  __syncthreads();
  const int seg = blockIdx.x * 4 + (tid >> 6);
  if (seg >= M) return;
  const int lane = tid & 63;
  const int lo = offsets[seg], hi = offsets[seg + 1];
  float acc = -3.402823466e38f;
  #pragma unroll 1
  for (int i = lo; i < hi; ++i) {
    const int node = perm[i];
    const int g = gidx[node];
    const unsigned short hb = h2[(size_t)node * 64 + lane];   // 128B/wave coalesced
    const float v = __uint_as_float((unsigned int)hb << 16);
    float y = fmaf(v, a2s[g * 64 + lane], c2s[g * 64 + lane]);
    y = y >= 0.f ? y : y * SLOPE;
    acc = fmaxf(acc, y);
  }
  out[(size_t)seg * 64 + lane] = (hi > lo) ? acc : 0.0f;
}

// ---- fallback (R5 path) when ws too small for index arrays ----
__global__ __launch_bounds__(256) void k5_scatter(
    const unsigned int* __restrict__ h2, const int* __restrict__ gidx,
    const int* __restrict__ sidx, const float* __restrict__ ws,
    unsigned int* __restrict__ out, int N) {
  int t = blockIdx.x * 256 + threadIdx.x;
  int node = t >> 4;
  if (node >= N) return;
  int jq = t & 15, j = jq * 4;
  int g = gidx[node];
  int sp = sidx[node];
  float4 av = *(const float4*)(ws + OFF_A2 + g * 64 + j);
  float4 cv = *(const float4*)(ws + OFF_C2 + g * 64 + j);
  uint2 hv = *(const uint2*)(h2 + (size_t)node * 32 + jq * 2);
  float v0 = __uint_as_float(hv.x << 16);
  float v1 = __uint_as_float(hv.x & 0xFFFF0000u);
  float v2 = __uint_as_float(hv.y << 16);
  float v3 = __uint_as_float(hv.y & 0xFFFF0000u);
  v0 = fmaf(v0, av.x, cv.x); v0 = v0 >= 0.f ? v0 : v0 * SLOPE;
  v1 = fmaf(v1, av.y, cv.y); v1 = v1 >= 0.f ? v1 : v1 * SLOPE;
  v2 = fmaf(v2, av.z, cv.z); v2 = v2 >= 0.f ? v2 : v2 * SLOPE;
  v3 = fmaf(v3, av.w, cv.w); v3 = v3 >= 0.f ? v3 : v3 * SLOPE;
  unsigned int* o = out + (size_t)sp * 64 + j;
  atomicMax(o + 0, enc_f32(v0));
  atomicMax(o + 1, enc_f32(v1));
  atomicMax(o + 2, enc_f32(v2));
  atomicMax(o + 3, enc_f32(v3));
}

__global__ void k6_decode(unsigned int* __restrict__ o, int n) {
  int i = blockIdx.x * 256 + threadIdx.x;
  if (i >= n) return;
  unsigned int e = o[i];
  float f;
  if (e == 0u) f = 0.0f;
  else if (e & 0x80000000u) f = __uint_as_float(e ^ 0x80000000u);
  else f = __uint_as_float(~e);
  ((float*)o)[i] = f;
}

extern "C" void kernel_launch(void* const* d_in, const int* in_sizes, int n_in,
                              void* d_out, int out_size, void* d_ws, size_t ws_size,
                              hipStream_t stream) {
  const float* x   = (const float*)d_in[0];
  const float* W1  = (const float*)d_in[1];
  const float* b1  = (const float*)d_in[2];
  const float* g1  = (const float*)d_in[3];
  const float* be1 = (const float*)d_in[4];
  const float* W2  = (const float*)d_in[5];
  const float* b2  = (const float*)d_in[6];
  const float* g2  = (const float*)d_in[7];
  const float* be2 = (const float*)d_in[8];
  const int* gidx  = (const int*)d_in[9];
  const int* sidx  = (const int*)d_in[10];
  const int N = in_sizes[9];
  const int M = out_size / 64;
  float* ws = (float*)d_ws;
  unsigned short* h2 = (unsigned short*)((char*)d_ws + H2_BYTE_OFF);
  unsigned int* out_u = (unsigned int*)d_out;

  // index arrays after h2
  const size_t idx_off = (size_t)H2_BYTE_OFF + (size_t)N * 128;
  int* hist    = (int*)((char*)d_ws + idx_off);
  int* cursor  = hist + M;
  int* offsets = cursor + M;            // M+1 entries
  int* perm    = offsets + M + 1;
  const size_t needed_fast = idx_off + (size_t)(3 * M + 1 + N) * 4;
  const bool fast = (ws_size >= needed_fast);

  const int zthreads = ZERO_SMALL + M_FLOATS;
  hipLaunchKernelGGL(k_zero_stats, dim3((zthreads + 255) / 256), dim3(256), 0, stream, ws);
  hipLaunchKernelGGL(k1_mom, dim3(1024), dim3(256), 0, stream, x, gidx, ws, N);
  hipLaunchKernelGGL(k2a_fin1, dim3(NGRAPH), dim3(128), 0, stream, W1, b1, g1, be1, ws);
  const int ntiles = (N + 15) / 16;
  const int tpb = (ntiles + 1023) / 1024;
  const int k3blocks = (ntiles + tpb - 1) / tpb;
  hipLaunchKernelGGL(k3_mfma, dim3(k3blocks), dim3(256), 0, stream,
                     x, W1, W2, b2, gidx, ws, h2, N, ntiles, tpb);
  hipLaunchKernelGGL(k2_fin, dim3((NGRAPH * 64 + 255) / 256), dim3(256), 0, stream,
                     ws, g2, be2, 64, OFF_SUM2, OFF_SQ2, OFF_A2, OFF_C2);
  if (fast) {
    hipLaunchKernelGGL(k_zero_ints, dim3((M + 255) / 256), dim3(256), 0, stream, hist, M);
    hipLaunchKernelGGL(k5a_hist, dim3((N + 255) / 256), dim3(256), 0, stream, sidx, hist, N);
    hipLaunchKernelGGL(k5b_scan, dim3(1), dim3(256), 0, stream, hist, offsets, cursor, M, N);
    hipLaunchKernelGGL(k5c_perm, dim3((N + 255) / 256), dim3(256), 0, stream,
                       sidx, cursor, perm, N);
    hipLaunchKernelGGL(k5d_gather, dim3((M + 3) / 4), dim3(256), 0, stream,
                       h2, perm, offsets, gidx, ws, (float*)d_out, M);
  } else {
    hipLaunchKernelGGL(k_init_out, dim3((out_size + 255) / 256), dim3(256), 0, stream,
                       out_u, out_size);
    hipLaunchKernelGGL(k5_scatter, dim3((N * 16 + 255) / 256), dim3(256), 0, stream,
                       (const unsigned int*)h2, gidx, sidx, ws, out_u, N);
    hipLaunchKernelGGL(k6_decode, dim3((out_size + 255) / 256), dim3(256), 0, stream,
                       out_u, out_size);
  }
}

// Round 9
// 1030.737 us; speedup vs baseline: 11.0351x; 1.0993x over previous
//
#include <hip/hip_runtime.h>
#include <hip/hip_bf16.h>
#include <stdint.h>

#define NGRAPH 16
#define EPSV 1e-5f
#define SLOPE 0.01f

// ---- ws float-offset layout ----
#define OFF_S1   0       // [16][32]  segment-sum of x (bf16-rounded)
#define OFF_CNT  512     // [16]
#define OFF_SUM2 528     // [16][64]
#define OFF_SQ2  1552    // [16][64]
#define ZERO_SMALL 2576
#define OFF_A1   2576    // [16][128]
#define OFF_C1   4624    // [16][128]
#define OFF_A2   6672    // [16][64]
#define OFF_C2   7696    // [16][64]
// M_g (16 x 32 x 32 f32 = 64 KB) at byte 65536, OVERLAPPING h2 (consumed
// by k2a before k3 writes h2).
#define OFF_M    16384
#define M_FLOATS 16384
#define H2_BYTE_OFF 65536   // bf16 h2 [N][64]

typedef __attribute__((ext_vector_type(4))) float f32x4;
typedef __attribute__((ext_vector_type(8))) short short8v;

__device__ __forceinline__ unsigned int enc_f32(float f) {
  unsigned int b = __float_as_uint(f);
  return (b & 0x80000000u) ? ~b : (b | 0x80000000u);
}
__device__ __forceinline__ unsigned int f2bf_bits(float f) {
  unsigned int u = __float_as_uint(f);
  unsigned int r = u + 0x7FFFu + ((u >> 16) & 1u);
  return r >> 16;
}
__device__ __forceinline__ float bfround(float f) {
  unsigned int u = __float_as_uint(f);
  unsigned int r = (u + 0x7FFFu + ((u >> 16) & 1u)) & 0xFFFF0000u;
  return __uint_as_float(r);
}

// zero small stats + M region + (fast path) hist ints, one launch
__global__ void k_zero_all(float* __restrict__ ws, int* __restrict__ hist, int M) {
  int i = blockIdx.x * 256 + threadIdx.x;
  if (i < ZERO_SMALL) ws[i] = 0.0f;
  if (i < M_FLOATS) ws[OFF_M + i] = 0.0f;
  if (i < M) hist[i] = 0;
}

__global__ void k_init_out(unsigned int* __restrict__ out, int n) {
  int i = blockIdx.x * 256 + threadIdx.x;
  if (i < n) out[i] = 0u;
}

// K1: per-graph second moments M_g = sum x x^T, s_g, cnt over bf16-rounded x.
// 1-deep register prefetch of next node's x row + gidx (latency hiding).
__global__ __launch_bounds__(256) void k1_mom(
    const float* __restrict__ x, const int* __restrict__ gidx,
    float* __restrict__ ws, int N) {
  const int tid = threadIdx.x;
  const int gw = blockIdx.x * 4 + (tid >> 6);
  const int l = tid & 63;
  const int bi = l >> 3, bj = l & 7;
  const bool diag = (bi == bj);
  const bool isL0 = (l == 0);
  const int nwaves = gridDim.x * 4;
  const int npw = (N + nwaves - 1) / nwaves;
  const int n0 = gw * npw;
  const int n1 = min(n0 + npw, N);

  float m00,m01,m02,m03,m10,m11,m12,m13,m20,m21,m22,m23,m30,m31,m32,m33;
  m00=m01=m02=m03=m10=m11=m12=m13=m20=m21=m22=m23=m30=m31=m32=m33=0.f;
  float sv0=0.f, sv1=0.f, sv2=0.f, sv3=0.f, cnt=0.f;
  int curg = -1;

  if (n0 < n1) {
    const int nlast = n1 - 1;
    int g = gidx[n0];
    float4 pi = *(const float4*)(x + (size_t)n0 * 32 + bi * 4);
    float4 pj = *(const float4*)(x + (size_t)n0 * 32 + bj * 4);
    #pragma unroll 1
    for (int n = n0; n < n1; ++n) {
      const int nn = min(n + 1, nlast);
      const int g2 = gidx[nn];                                   // prefetch
      float4 pi2 = *(const float4*)(x + (size_t)nn * 32 + bi * 4);
      float4 pj2 = *(const float4*)(x + (size_t)nn * 32 + bj * 4);
      if (g != curg) {
        if (curg >= 0) {
          float* Mg = ws + OFF_M + curg * 1024 + bi * 4 * 32 + bj * 4;
          atomicAdd(Mg + 0*32 + 0, m00); atomicAdd(Mg + 0*32 + 1, m01);
          atomicAdd(Mg + 0*32 + 2, m02); atomicAdd(Mg + 0*32 + 3, m03);
          atomicAdd(Mg + 1*32 + 0, m10); atomicAdd(Mg + 1*32 + 1, m11);
          atomicAdd(Mg + 1*32 + 2, m12); atomicAdd(Mg + 1*32 + 3, m13);
          atomicAdd(Mg + 2*32 + 0, m20); atomicAdd(Mg + 2*32 + 1, m21);
          atomicAdd(Mg + 2*32 + 2, m22); atomicAdd(Mg + 2*32 + 3, m23);
          atomicAdd(Mg + 3*32 + 0, m30); atomicAdd(Mg + 3*32 + 1, m31);
          atomicAdd(Mg + 3*32 + 2, m32); atomicAdd(Mg + 3*32 + 3, m33);
          if (diag) {
            float* Sg = ws + OFF_S1 + curg * 32 + bi * 4;
            atomicAdd(Sg + 0, sv0); atomicAdd(Sg + 1, sv1);
            atomicAdd(Sg + 2, sv2); atomicAdd(Sg + 3, sv3);
          }
          if (isL0) atomicAdd(ws + OFF_CNT + curg, cnt);
        }
        curg = g;
        m00=m01=m02=m03=m10=m11=m12=m13=m20=m21=m22=m23=m30=m31=m32=m33=0.f;
        sv0=sv1=sv2=sv3=0.f; cnt=0.f;
      }
      float xi0 = bfround(pi.x), xi1 = bfround(pi.y), xi2 = bfround(pi.z), xi3 = bfround(pi.w);
      float xj0 = bfround(pj.x), xj1 = bfround(pj.y), xj2 = bfround(pj.z), xj3 = bfround(pj.w);
      m00 = fmaf(xi0,xj0,m00); m01 = fmaf(xi0,xj1,m01); m02 = fmaf(xi0,xj2,m02); m03 = fmaf(xi0,xj3,m03);
      m10 = fmaf(xi1,xj0,m10); m11 = fmaf(xi1,xj1,m11); m12 = fmaf(xi1,xj2,m12); m13 = fmaf(xi1,xj3,m13);
      m20 = fmaf(xi2,xj0,m20); m21 = fmaf(xi2,xj1,m21); m22 = fmaf(xi2,xj2,m22); m23 = fmaf(xi2,xj3,m23);
      m30 = fmaf(xi3,xj0,m30); m31 = fmaf(xi3,xj1,m31); m32 = fmaf(xi3,xj2,m32); m33 = fmaf(xi3,xj3,m33);
      if (diag) { sv0 += xi0; sv1 += xi1; sv2 += xi2; sv3 += xi3; }
      cnt += 1.f;
      pi = pi2; pj = pj2; g = g2;
    }
  }
  if (curg >= 0) {
    float* Mg = ws + OFF_M + curg * 1024 + bi * 4 * 32 + bj * 4;
    atomicAdd(Mg + 0*32 + 0, m00); atomicAdd(Mg + 0*32 + 1, m01);
    atomicAdd(Mg + 0*32 + 2, m02); atomicAdd(Mg + 0*32 + 3, m03);
    atomicAdd(Mg + 1*32 + 0, m10); atomicAdd(Mg + 1*32 + 1, m11);
    atomicAdd(Mg + 1*32 + 2, m12); atomicAdd(Mg + 1*32 + 3, m13);
    atomicAdd(Mg + 2*32 + 0, m20); atomicAdd(Mg + 2*32 + 1, m21);
    atomicAdd(Mg + 2*32 + 2, m22); atomicAdd(Mg + 2*32 + 3, m23);
    atomicAdd(Mg + 3*32 + 0, m30); atomicAdd(Mg + 3*32 + 1, m31);
    atomicAdd(Mg + 3*32 + 2, m32); atomicAdd(Mg + 3*32 + 3, m33);
    if (diag) {
      float* Sg = ws + OFF_S1 + curg * 32 + bi * 4;
      atomicAdd(Sg + 0, sv0); atomicAdd(Sg + 1, sv1);
      atomicAdd(Sg + 2, sv2); atomicAdd(Sg + 3, sv3);
    }
    if (isL0) atomicAdd(ws + OFF_CNT + curg, cnt);
  }
}

// K2a: layer-1 stats from moments (rounding identical to k3's MFMA inputs).
__global__ __launch_bounds__(128) void k2a_fin1(
    const float* __restrict__ W1, const float* __restrict__ b1,
    const float* __restrict__ g1, const float* __restrict__ be1,
    float* __restrict__ ws) {
  __shared__ float Ms[1024];
  __shared__ float ss[32];
  __shared__ float cs;
  const int g = blockIdx.x, c = threadIdx.x;
  for (int i = c; i < 1024; i += 128) Ms[i] = ws[OFF_M + g * 1024 + i];
  if (c < 32) ss[c] = ws[OFF_S1 + g * 32 + c];
  if (c == 0) cs = fmaxf(ws[OFF_CNT + g], 1.0f);
  __syncthreads();
  float w[32];
  #pragma unroll
  for (int k = 0; k < 32; ++k) w[k] = bfround(W1[c * 32 + k]);
  float dot = 0.f;
  #pragma unroll
  for (int k = 0; k < 32; ++k) dot = fmaf(w[k], ss[k], dot);
  float quad = 0.f;
  #pragma unroll 1
  for (int i = 0; i < 32; ++i) {
    const float* Mr = Ms + i * 32;
    float acc = 0.f;
    #pragma unroll
    for (int j = 0; j < 32; ++j) acc = fmaf(Mr[j], w[j], acc);
    quad = fmaf(w[i], acc, quad);
  }
  const float cnt = cs;
  const float bc = b1[c];
  const float mean = dot / cnt + bc;
  const float e2 = (quad + 2.f * bc * dot) / cnt + bc * bc;
  const float var = fmaxf(e2 - mean * mean, 0.0f);
  const float a = rsqrtf(var + EPSV) * g1[c];
  ws[OFF_A1 + g * 128 + c] = a;
  ws[OFF_C1 + g * 128 + c] = fmaf(a, bc - mean, be1[c]);
}

// K2: finalize layer-2 stats -> A2 = rstd*gamma, C2 = beta - mean*A2
__global__ void k2_fin(float* __restrict__ ws, const float* __restrict__ gamma,
                       const float* __restrict__ beta, int D, int off_sum,
                       int off_sq, int off_a, int off_c) {
  int i = blockIdx.x * 256 + threadIdx.x;
  if (i >= NGRAPH * D) return;
  int g = i / D, c = i % D;
  float cnt  = fmaxf(ws[OFF_CNT + g], 1.0f);
  float mean = ws[off_sum + i] / cnt;
  float ex2  = ws[off_sq + i] / cnt;
  float var  = fmaxf(ex2 - mean * mean, 0.0f);
  float a = rsqrtf(var + EPSV) * gamma[c];
  ws[off_a + i] = a;
  ws[off_c + i] = fmaf(-mean, a, beta[c]);
}

// K3: MFMA pipeline. No per-tile __syncthreads (h1t is wave-private;
// same-wave ds ordering via explicit lgkmcnt fence + sched_barrier).
// Contiguous per-wave tile ranges; 1-deep register prefetch of next tile.
__global__ __launch_bounds__(256) void k3_mfma(
    const float* __restrict__ x, const float* __restrict__ W1,
    const float* __restrict__ W2, const float* __restrict__ b2,
    const int* __restrict__ gidx, float* __restrict__ ws,
    unsigned short* __restrict__ h2out, int N, int ntiles, int tpw) {
  __shared__ float a1s[2048];
  __shared__ float c1s[2048];
  __shared__ __align__(16) unsigned short h1t[4][2048];
  const int tid = threadIdx.x;
  const int wv = tid >> 6;
  const int l = tid & 63;
  const int ln = l & 15;
  const int kq = l >> 4;

  for (int i = tid; i < 2048; i += 256) { a1s[i] = ws[OFF_A1 + i]; c1s[i] = ws[OFF_C1 + i]; }

  short8v w1f[8];
  #pragma unroll
  for (int t = 0; t < 8; ++t) {
    const float* wr = W1 + (size_t)(t * 16 + ln) * 32 + kq * 8;
    float4 p = *(const float4*)wr, q = *(const float4*)(wr + 4);
    short8v f;
    f[0] = (short)f2bf_bits(p.x); f[1] = (short)f2bf_bits(p.y);
    f[2] = (short)f2bf_bits(p.z); f[3] = (short)f2bf_bits(p.w);
    f[4] = (short)f2bf_bits(q.x); f[5] = (short)f2bf_bits(q.y);
    f[6] = (short)f2bf_bits(q.z); f[7] = (short)f2bf_bits(q.w);
    w1f[t] = f;
  }
  short8v w2f[4][4];
  #pragma unroll
  for (int ct = 0; ct < 4; ++ct)
    #pragma unroll
    for (int kt = 0; kt < 4; ++kt) {
      const float* wr = W2 + (size_t)(ct * 16 + ln) * 128 + kt * 32 + kq * 8;
      float4 p = *(const float4*)wr, q = *(const float4*)(wr + 4);
      short8v f;
      f[0] = (short)f2bf_bits(p.x); f[1] = (short)f2bf_bits(p.y);
      f[2] = (short)f2bf_bits(p.z); f[3] = (short)f2bf_bits(p.w);
      f[4] = (short)f2bf_bits(q.x); f[5] = (short)f2bf_bits(q.y);
      f[6] = (short)f2bf_bits(q.z); f[7] = (short)f2bf_bits(q.w);
      w2f[ct][kt] = f;
    }
  float b2v[4];
  #pragma unroll
  for (int ct = 0; ct < 4; ++ct) b2v[ct] = b2[ct * 16 + ln];
  __syncthreads();   // only barrier: a1s/c1s staging (read-only afterwards)

  const int gw = blockIdx.x * 4 + wv;
  const int t0 = gw * tpw;
  const int t1 = min(t0 + tpw, ntiles);
  if (t0 >= t1) return;

  unsigned short* myt = &h1t[wv][0];
  const f32x4 zero4 = {0.f, 0.f, 0.f, 0.f};
  float s2[4] = {0.f, 0.f, 0.f, 0.f}, q2a[4] = {0.f, 0.f, 0.f, 0.f};
  int curg2 = -1;

  // prologue: load tile t0
  float4 p, q;
  int gg[4];
  {
    const int base = t0 * 16;
    const float* xr = x + (size_t)min(base + ln, N - 1) * 32 + kq * 8;
    p = *(const float4*)xr; q = *(const float4*)(xr + 4);
    #pragma unroll
    for (int i = 0; i < 4; ++i) gg[i] = gidx[min(base + kq * 4 + i, N - 1)];
  }

  #pragma unroll 1
  for (int t = t0; t < t1; ++t) {
    const int base = t * 16;
    // prefetch next tile (clamped; duplicate load on last iter is harmless)
    float4 p2, q2;
    int gg2[4];
    {
      const int nb = min(t + 1, t1 - 1) * 16;
      const float* xr = x + (size_t)min(nb + ln, N - 1) * 32 + kq * 8;
      p2 = *(const float4*)xr; q2 = *(const float4*)(xr + 4);
      #pragma unroll
      for (int i = 0; i < 4; ++i) gg2[i] = gidx[min(nb + kq * 4 + i, N - 1)];
    }
    // ---- layer 1 ----
    short8v af;
    af[0] = (short)f2bf_bits(p.x); af[1] = (short)f2bf_bits(p.y);
    af[2] = (short)f2bf_bits(p.z); af[3] = (short)f2bf_bits(p.w);
    af[4] = (short)f2bf_bits(q.x); af[5] = (short)f2bf_bits(q.y);
    af[6] = (short)f2bf_bits(q.z); af[7] = (short)f2bf_bits(q.w);
    f32x4 acc1[8];
    #pragma unroll
    for (int tt = 0; tt < 8; ++tt)
      acc1[tt] = __builtin_amdgcn_mfma_f32_16x16x32_bf16(af, w1f[tt], zero4, 0, 0, 0);
    // normalize + leaky -> swizzled wave-private LDS (bf16)
    #pragma unroll
    for (int tt = 0; tt < 8; ++tt) {
      const int ct_ = tt * 16 + ln;
      #pragma unroll
      for (int i = 0; i < 4; ++i) {
        const float a = a1s[gg[i] * 128 + ct_];
        const float cc = c1s[gg[i] * 128 + ct_];
        float v = fmaf(acc1[tt][i], a, cc);
        v = v >= 0.f ? v : v * SLOPE;
        const int row = kq * 4 + i;
        const int byte = (row * 256 + ct_ * 2) ^ ((row & 7) << 4);
        *(unsigned short*)((char*)myt + byte) = (unsigned short)f2bf_bits(v);
      }
    }
    // same-wave ds_write -> ds_read fence (rule #18 belt-and-braces)
    asm volatile("s_waitcnt lgkmcnt(0)" ::: "memory");
    __builtin_amdgcn_sched_barrier(0);
    // ---- layer 2 ----
    short8v a2f[4];
    #pragma unroll
    for (int kt = 0; kt < 4; ++kt) {
      const int byte = (ln * 256 + kt * 64 + kq * 16) ^ ((ln & 7) << 4);
      a2f[kt] = *(const short8v*)((const char*)myt + byte);
    }
    f32x4 acc2[4];
    #pragma unroll
    for (int ct = 0; ct < 4; ++ct) {
      f32x4 a = zero4;
      #pragma unroll
      for (int kt = 0; kt < 4; ++kt)
        a = __builtin_amdgcn_mfma_f32_16x16x32_bf16(a2f[kt], w2f[ct][kt], a, 0, 0, 0);
      acc2[ct] = a;
    }
    // stats2 (run-length) + h2 store
    #pragma unroll
    for (int i = 0; i < 4; ++i) {
      const int node = base + kq * 4 + i;
      if (node >= N) break;
      const int g = gg[i];
      if (g != curg2) {
        if (curg2 >= 0) {
          #pragma unroll
          for (int ct = 0; ct < 4; ++ct) {
            atomicAdd(ws + OFF_SUM2 + curg2 * 64 + ct * 16 + ln, s2[ct]);
            atomicAdd(ws + OFF_SQ2  + curg2 * 64 + ct * 16 + ln, q2a[ct]);
          }
        }
        curg2 = g;
        #pragma unroll
        for (int ct = 0; ct < 4; ++ct) { s2[ct] = 0.f; q2a[ct] = 0.f; }
      }
      #pragma unroll
      for (int ct = 0; ct < 4; ++ct) {
        const float v2 = acc2[ct][i] + b2v[ct];
        s2[ct] += v2; q2a[ct] = fmaf(v2, v2, q2a[ct]);
        h2out[(size_t)node * 64 + ct * 16 + ln] = (unsigned short)f2bf_bits(v2);
      }
    }
    p = p2; q = q2;
    #pragma unroll
    for (int i = 0; i < 4; ++i) gg[i] = gg2[i];
  }
  if (curg2 >= 0) {
    #pragma unroll
    for (int ct = 0; ct < 4; ++ct) {
      atomicAdd(ws + OFF_SUM2 + curg2 * 64 + ct * 16 + ln, s2[ct]);
      atomicAdd(ws + OFF_SQ2  + curg2 * 64 + ct * 16 + ln, q2a[ct]);
    }
  }
}

// ---- scatter-max via counting-sort inverse index ----
__global__ void k5a_hist(const int* __restrict__ sidx, int* __restrict__ hist, int N) {
  int n = blockIdx.x * 256 + threadIdx.x;
  if (n < N) atomicAdd(&hist[sidx[n]], 1);
}

__global__ __launch_bounds__(256) void k5b_scan(
    const int* __restrict__ hist, int* __restrict__ offsets,
    int* __restrict__ cursor, int M, int N) {
  __shared__ int part[256];
  const int tid = threadIdx.x;
  const int chunk = (M + 255) / 256;
  const int lo = min(tid * chunk, M), hi = min(lo + chunk, M);
  int s = 0;
  for (int i = lo; i < hi; ++i) s += hist[i];
  part[tid] = s;
  __syncthreads();
  if (tid == 0) {
    int run = 0;
    for (int i = 0; i < 256; ++i) { int v = part[i]; part[i] = run; run += v; }
  }
  __syncthreads();
  int run = part[tid];
  for (int i = lo; i < hi; ++i) {
    int v = hist[i];
    offsets[i] = run; cursor[i] = run; run += v;
  }
  if (tid == 255) offsets[M] = N;
}

// k5c: scatter PACKED (node<<4 | graph) ids — kills k5d's dependent gidx load
__global__ void k5c_perm(const int* __restrict__ sidx, const int* __restrict__ gidx,
                         int* __restrict__ cursor, int* __restrict__ perm, int N) {
  int n = blockIdx.x * 256 + threadIdx.x;
  if (n >= N) return;
  int sp = sidx[n];
  int pos = atomicAdd(&cursor[sp], 1);
  perm[pos] = (n << 4) | (gidx[n] & 15);
}

// k5d: one wave per segment, lane = channel; 2-deep pipeline on perm->h2.
__global__ __launch_bounds__(256) void k5d_gather(
    const unsigned short* __restrict__ h2, const int* __restrict__ perm,
    const int* __restrict__ offsets, const float* __restrict__ ws,
    float* __restrict__ out, int M) {
  __shared__ float a2s[1024], c2s[1024];
  const int tid = threadIdx.x;
  for (int i = tid; i < 1024; i += 256) { a2s[i] = ws[OFF_A2 + i]; c2s[i] = ws[OFF_C2 + i]; }
  __syncthreads();
  const int seg = blockIdx.x * 4 + (tid >> 6);
  if (seg >= M) return;
  const int lane = tid & 63;
  const int lo = offsets[seg], hi = offsets[seg + 1];
  float acc = -3.402823466e38f;
  if (hi > lo) {
    const int last = hi - 1;
    int pc = perm[lo];
    unsigned short hc = h2[(size_t)(pc >> 4) * 64 + lane];
    int pn = perm[min(lo + 1, last)];
    #pragma unroll 1
    for (int i = lo; i < hi; ++i) {
      const unsigned short hn = h2[(size_t)(pn >> 4) * 64 + lane];  // prefetch
      const int pn2 = perm[min(i + 2, last)];
      const int g = pc & 15;
      const float v = __uint_as_float((unsigned int)hc << 16);
      float y = fmaf(v, a2s[g * 64 + lane], c2s[g * 64 + lane]);
      y = y >= 0.f ? y : y * SLOPE;
      acc = fmaxf(acc, y);
      pc = pn; hc = hn; pn = pn2;
    }
  }
  out[(size_t)seg * 64 + lane] = (hi > lo) ? acc : 0.0f;
}

// ---- fallback (atomic path) when ws too small for index arrays ----
__global__ __launch_bounds__(256) void k5_scatter(
    const unsigned int* __restrict__ h2, const int* __restrict__ gidx,
    const int* __restrict__ sidx, const float* __restrict__ ws,
    unsigned int* __restrict__ out, int N) {
  int t = blockIdx.x * 256 + threadIdx.x;
  int node = t >> 4;
  if (node >= N) return;
  int jq = t & 15, j = jq * 4;
  int g = gidx[node];
  int sp = sidx[node];
  float4 av = *(const float4*)(ws + OFF_A2 + g * 64 + j);
  float4 cv = *(const float4*)(ws + OFF_C2 + g * 64 + j);
  uint2 hv = *(const uint2*)(h2 + (size_t)node * 32 + jq * 2);
  float v0 = __uint_as_float(hv.x << 16);
  float v1 = __uint_as_float(hv.x & 0xFFFF0000u);
  float v2 = __uint_as_float(hv.y << 16);
  float v3 = __uint_as_float(hv.y & 0xFFFF0000u);
  v0 = fmaf(v0, av.x, cv.x); v0 = v0 >= 0.f ? v0 : v0 * SLOPE;
  v1 = fmaf(v1, av.y, cv.y); v1 = v1 >= 0.f ? v1 : v1 * SLOPE;
  v2 = fmaf(v2, av.z, cv.z); v2 = v2 >= 0.f ? v2 : v2 * SLOPE;
  v3 = fmaf(v3, av.w, cv.w); v3 = v3 >= 0.f ? v3 : v3 * SLOPE;
  unsigned int* o = out + (size_t)sp * 64 + j;
  atomicMax(o + 0, enc_f32(v0));
  atomicMax(o + 1, enc_f32(v1));
  atomicMax(o + 2, enc_f32(v2));
  atomicMax(o + 3, enc_f32(v3));
}

__global__ void k6_decode(unsigned int* __restrict__ o, int n) {
  int i = blockIdx.x * 256 + threadIdx.x;
  if (i >= n) return;
  unsigned int e = o[i];
  float f;
  if (e == 0u) f = 0.0f;
  else if (e & 0x80000000u) f = __uint_as_float(e ^ 0x80000000u);
  else f = __uint_as_float(~e);
  ((float*)o)[i] = f;
}

extern "C" void kernel_launch(void* const* d_in, const int* in_sizes, int n_in,
                              void* d_out, int out_size, void* d_ws, size_t ws_size,
                              hipStream_t stream) {
  const float* x   = (const float*)d_in[0];
  const float* W1  = (const float*)d_in[1];
  const float* b1  = (const float*)d_in[2];
  const float* g1  = (const float*)d_in[3];
  const float* be1 = (const float*)d_in[4];
  const float* W2  = (const float*)d_in[5];
  const float* b2  = (const float*)d_in[6];
  const float* g2  = (const float*)d_in[7];
  const float* be2 = (const float*)d_in[8];
  const int* gidx  = (const int*)d_in[9];
  const int* sidx  = (const int*)d_in[10];
  const int N = in_sizes[9];
  const int M = out_size / 64;
  float* ws = (float*)d_ws;
  unsigned short* h2 = (unsigned short*)((char*)d_ws + H2_BYTE_OFF);
  unsigned int* out_u = (unsigned int*)d_out;

  const size_t idx_off = (size_t)H2_BYTE_OFF + (size_t)N * 128;
  int* hist    = (int*)((char*)d_ws + idx_off);
  int* cursor  = hist + M;
  int* offsets = cursor + M;            // M+1 entries
  int* perm    = offsets + M + 1;
  const size_t needed_fast = idx_off + (size_t)(3 * M + 1 + N) * 4;
  const bool fast = (ws_size >= needed_fast);

  const int zmax = (M_FLOATS > M ? M_FLOATS : M);
  hipLaunchKernelGGL(k_zero_all, dim3((zmax + 255) / 256), dim3(256), 0, stream,
                     ws, hist, fast ? M : 0);
  hipLaunchKernelGGL(k1_mom, dim3(1024), dim3(256), 0, stream, x, gidx, ws, N);
  hipLaunchKernelGGL(k2a_fin1, dim3(NGRAPH), dim3(128), 0, stream, W1, b1, g1, be1, ws);
  if (fast) {
    hipLaunchKernelGGL(k5a_hist, dim3((N + 255) / 256), dim3(256), 0, stream, sidx, hist, N);
    hipLaunchKernelGGL(k5b_scan, dim3(1), dim3(256), 0, stream, hist, offsets, cursor, M, N);
    hipLaunchKernelGGL(k5c_perm, dim3((N + 255) / 256), dim3(256), 0, stream,
                       sidx, gidx, cursor, perm, N);
  }
  const int ntiles = (N + 15) / 16;
  const int NW = 4096;                       // target wave count
  const int tpw = (ntiles + NW - 1) / NW;    // tiles per wave
  const int k3blocks = (ntiles + 4 * tpw - 1) / (4 * tpw);
  hipLaunchKernelGGL(k3_mfma, dim3(k3blocks), dim3(256), 0, stream,
                     x, W1, W2, b2, gidx, ws, h2, N, ntiles, tpw);
  hipLaunchKernelGGL(k2_fin, dim3((NGRAPH * 64 + 255) / 256), dim3(256), 0, stream,
                     ws, g2, be2, 64, OFF_SUM2, OFF_SQ2, OFF_A2, OFF_C2);
  if (fast) {
    hipLaunchKernelGGL(k5d_gather, dim3((M + 3) / 4), dim3(256), 0, stream,
                       h2, perm, offsets, ws, (float*)d_out, M);
  } else {
    hipLaunchKernelGGL(k_init_out, dim3((out_size + 255) / 256), dim3(256), 0, stream,
                       out_u, out_size);
    hipLaunchKernelGGL(k5_scatter, dim3((N * 16 + 255) / 256), dim3(256), 0, stream,
                       (const unsigned int*)h2, gidx, sidx, ws, out_u, N);
    hipLaunchKernelGGL(k6_decode, dim3((out_size + 255) / 256), dim3(256), 0, stream,
                       out_u, out_size);
  }
}

// Round 10
// 910.495 us; speedup vs baseline: 12.4925x; 1.1321x over previous
//
#include <hip/hip_runtime.h>
#include <hip/hip_bf16.h>
#include <stdint.h>

#define NGRAPH 16
#define EPSV 1e-5f
#define SLOPE 0.01f

// ---- ws float-offset layout ----
#define OFF_S1   0       // [16][32]  segment-sum of x (bf16-rounded)
#define OFF_CNT  512     // [16]
#define OFF_SUM2 528     // [16][64]
#define OFF_SQ2  1552    // [16][64]
#define ZERO_SMALL 2576
#define OFF_A1   2576    // [16][128]
#define OFF_C1   4624    // [16][128]
#define OFF_A2   6672    // [16][64]
#define OFF_C2   7696    // [16][64]
// M_g (16 x 32 x 32 f32 = 64 KB) at byte 65536, OVERLAPPING h2 (consumed
// by k2a before k3 writes h2).
#define OFF_M    16384
#define M_FLOATS 16384
#define H2_BYTE_OFF 65536   // bf16 h2 [N][64]

typedef __attribute__((ext_vector_type(4))) float f32x4;
typedef __attribute__((ext_vector_type(16))) float f32x16;
typedef __attribute__((ext_vector_type(8))) short short8v;

union pk4 { unsigned int u[4]; short8v v; };

// hw packed f32->bf16 (RNE on gfx950); %1 -> low16, %2 -> high16
__device__ __forceinline__ unsigned int cvtpk(float lo, float hi) {
  unsigned int r;
  asm("v_cvt_pk_bf16_f32 %0, %1, %2" : "=v"(r) : "v"(lo), "v"(hi));
  return r;
}
__device__ __forceinline__ unsigned int enc_f32(float f) {
  unsigned int b = __float_as_uint(f);
  return (b & 0x80000000u) ? ~b : (b | 0x80000000u);
}
__device__ __forceinline__ unsigned int f2bf_bits(float f) {
  unsigned int u = __float_as_uint(f);
  unsigned int r = u + 0x7FFFu + ((u >> 16) & 1u);
  return r >> 16;
}
__device__ __forceinline__ float bfround(float f) {
  unsigned int u = __float_as_uint(f);
  unsigned int r = (u + 0x7FFFu + ((u >> 16) & 1u)) & 0xFFFF0000u;
  return __uint_as_float(r);
}
__device__ __forceinline__ float leaky(float v) {
  return fmaxf(v, 0.f) + SLOPE * fminf(v, 0.f);
}

__global__ void k_zero_all(float* __restrict__ ws, int* __restrict__ hist, int M) {
  int i = blockIdx.x * 256 + threadIdx.x;
  if (i < ZERO_SMALL) ws[i] = 0.0f;
  if (i < M_FLOATS) ws[OFF_M + i] = 0.0f;
  if (i < M) hist[i] = 0;
}

__global__ void k_init_out(unsigned int* __restrict__ out, int n) {
  int i = blockIdx.x * 256 + threadIdx.x;
  if (i < n) out[i] = 0u;
}

// K1 (R10): per-graph moments via MFMA. M_g = X^T X: one 32x32x16 MFMA per
// 16-node chunk, A=B=x fragment (lane: ch=l&31, nodes=(l>>5)*8+e). Graph
// boundaries (rare; norm_index sorted) via masked 2-pass. Flush = atomics.
__global__ __launch_bounds__(256) void k1_mom(
    const float* __restrict__ x, const int* __restrict__ gidx,
    float* __restrict__ ws, int N) {
  const int tid = threadIdx.x;
  const int gw = blockIdx.x * 4 + (tid >> 6);
  const int l = tid & 63;
  const int ch = l & 31;
  const int half = l >> 5;
  const int nchunks = (N + 15) / 16;
  const int nwaves = gridDim.x * 4;
  const int cpw = (nchunks + nwaves - 1) / nwaves;
  const int c0 = gw * cpw;
  const int c1 = min(c0 + cpw, nchunks);
  if (c0 >= c1) return;

  f32x16 acc;
  #pragma unroll
  for (int r = 0; r < 16; ++r) acc[r] = 0.f;
  float sv = 0.f, cnt = 0.f;
  int curg = -1;

  auto loadc = [&](int c, float* v, int& g0, int& gl) {
    const int nb = c * 16;
    #pragma unroll
    for (int e = 0; e < 8; ++e) {
      const int node = nb + half * 8 + e;
      v[e] = (node < N) ? x[(size_t)node * 32 + ch] : 0.f;
    }
    g0 = gidx[nb];
    gl = gidx[min(nb + 15, N - 1)];
  };
  auto flush = [&](int g) {
    float* Mg = ws + OFF_M + g * 1024;
    #pragma unroll
    for (int r = 0; r < 16; ++r) {
      const int row = (r & 3) + 8 * (r >> 2) + 4 * half;  // m74/m101 C layout
      atomicAdd(Mg + row * 32 + ch, acc[r]);
      acc[r] = 0.f;
    }
    atomicAdd(ws + OFF_S1 + g * 32 + ch, sv);
    if (l == 0) atomicAdd(ws + OFF_CNT + g, cnt);
    sv = 0.f; cnt = 0.f;
  };

  float v[8]; int g0, gl;
  loadc(c0, v, g0, gl);
  #pragma unroll 1
  for (int c = c0; c < c1; ++c) {
    float v2[8]; int g02, gl2;
    loadc(min(c + 1, c1 - 1), v2, g02, gl2);      // prefetch
    if (g0 != curg) { if (curg >= 0) flush(curg); curg = g0; }
    const int nb = c * 16;
    if (g0 == gl && nb + 16 <= N) {
      pk4 P;
      P.u[0] = cvtpk(v[0], v[1]); P.u[1] = cvtpk(v[2], v[3]);
      P.u[2] = cvtpk(v[4], v[5]); P.u[3] = cvtpk(v[6], v[7]);
      acc = __builtin_amdgcn_mfma_f32_32x32x16_bf16(P.v, P.v, acc, 0, 0, 0);
      #pragma unroll
      for (int e = 0; e < 4; ++e) {
        sv += __uint_as_float(P.u[e] << 16);
        sv += __uint_as_float(P.u[e] & 0xFFFF0000u);
      }
      if (l == 0) cnt += 16.f;
    } else {
      // rare: graph boundary or tail inside chunk (<= 2 graphs per chunk)
      int ge[8];
      #pragma unroll
      for (int e = 0; e < 8; ++e)
        ge[e] = gidx[min(nb + half * 8 + e, N - 1)];
      #pragma unroll 1
      for (int pass = 0; pass < 2; ++pass) {
        if (pass == 1) { if (gl == g0) break; flush(g0); curg = gl; }
        const int tg = (pass == 0) ? g0 : gl;
        float mv[8];
        #pragma unroll
        for (int e = 0; e < 8; ++e) {
          const int node = nb + half * 8 + e;
          mv[e] = (node < N && ge[e] == tg) ? v[e] : 0.f;
        }
        pk4 P;
        P.u[0] = cvtpk(mv[0], mv[1]); P.u[1] = cvtpk(mv[2], mv[3]);
        P.u[2] = cvtpk(mv[4], mv[5]); P.u[3] = cvtpk(mv[6], mv[7]);
        acc = __builtin_amdgcn_mfma_f32_32x32x16_bf16(P.v, P.v, acc, 0, 0, 0);
        #pragma unroll
        for (int e = 0; e < 4; ++e) {
          sv += __uint_as_float(P.u[e] << 16);
          sv += __uint_as_float(P.u[e] & 0xFFFF0000u);
        }
        if (l == 0) {
          float cc = 0.f;
          for (int i2 = 0; i2 < 16; ++i2) {
            const int node = nb + i2;
            if (node < N && gidx[node] == tg) cc += 1.f;
          }
          cnt += cc;
        }
      }
    }
    #pragma unroll
    for (int e = 0; e < 8; ++e) v[e] = v2[e];
    g0 = g02; gl = gl2;
  }
  if (curg >= 0) flush(curg);
}

// K2a: layer-1 stats from moments (W1 rounding matches k3's w1f).
__global__ __launch_bounds__(128) void k2a_fin1(
    const float* __restrict__ W1, const float* __restrict__ b1,
    const float* __restrict__ g1, const float* __restrict__ be1,
    float* __restrict__ ws) {
  __shared__ float Ms[1024];
  __shared__ float ss[32];
  __shared__ float cs;
  const int g = blockIdx.x, c = threadIdx.x;
  for (int i = c; i < 1024; i += 128) Ms[i] = ws[OFF_M + g * 1024 + i];
  if (c < 32) ss[c] = ws[OFF_S1 + g * 32 + c];
  if (c == 0) cs = fmaxf(ws[OFF_CNT + g], 1.0f);
  __syncthreads();
  float w[32];
  #pragma unroll
  for (int k = 0; k < 32; ++k) w[k] = bfround(W1[c * 32 + k]);
  float dot = 0.f;
  #pragma unroll
  for (int k = 0; k < 32; ++k) dot = fmaf(w[k], ss[k], dot);
  float quad = 0.f;
  #pragma unroll 1
  for (int i = 0; i < 32; ++i) {
    const float* Mr = Ms + i * 32;
    float acc = 0.f;
    #pragma unroll
    for (int j = 0; j < 32; ++j) acc = fmaf(Mr[j], w[j], acc);
    quad = fmaf(w[i], acc, quad);
  }
  const float cnt = cs;
  const float bc = b1[c];
  const float mean = dot / cnt + bc;
  const float e2 = (quad + 2.f * bc * dot) / cnt + bc * bc;
  const float var = fmaxf(e2 - mean * mean, 0.0f);
  const float a = rsqrtf(var + EPSV) * g1[c];
  ws[OFF_A1 + g * 128 + c] = a;
  ws[OFF_C1 + g * 128 + c] = fmaf(a, bc - mean, be1[c]);
}

// K2: finalize layer-2 stats -> A2 = rstd*gamma, C2 = beta - mean*A2
__global__ void k2_fin(float* __restrict__ ws, const float* __restrict__ gamma,
                       const float* __restrict__ beta, int D, int off_sum,
                       int off_sq, int off_a, int off_c) {
  int i = blockIdx.x * 256 + threadIdx.x;
  if (i >= NGRAPH * D) return;
  int g = i / D, c = i % D;
  float cnt  = fmaxf(ws[OFF_CNT + g], 1.0f);
  float mean = ws[off_sum + i] / cnt;
  float ex2  = ws[off_sq + i] / cnt;
  float var  = fmaxf(ex2 - mean * mean, 0.0f);
  float a = rsqrtf(var + EPSV) * gamma[c];
  ws[off_a + i] = a;
  ws[off_c + i] = fmaf(-mean, a, beta[c]);
}

// K3 (R10): swapped-operand MFMA pipeline, node-major C (lane owns 1 node),
// double-buffered wave-private LDS, produce(t+1) || consume(t), no fences
// (same-wave DS in-order; compiler tracks ds_read->MFMA register deps).
__global__ __launch_bounds__(256) void k3_mfma(
    const float* __restrict__ x, const float* __restrict__ W1,
    const float* __restrict__ W2, const float* __restrict__ b2,
    const int* __restrict__ gidx, const float* __restrict__ ws,
    unsigned short* __restrict__ h2out, int N, int ntiles, int tpw) {
  __shared__ float a1s[2048];
  __shared__ float c1s[2048];
  __shared__ __align__(16) unsigned short h1d[4][2][2048];  // 32KB dbuf
  const int tid = threadIdx.x, wv = tid >> 6, l = tid & 63;
  const int ln = l & 15, kq = l >> 4;
  const int swz = (ln & 7) << 4;

  for (int i = tid; i < 2048; i += 256) { a1s[i] = ws[OFF_A1 + i]; c1s[i] = ws[OFF_C1 + i]; }

  short8v w1f[8];   // A-frag: W1[ch=tt*16+ln][k=kq*8+e]
  #pragma unroll
  for (int t = 0; t < 8; ++t) {
    const float* wr = W1 + (size_t)(t * 16 + ln) * 32 + kq * 8;
    float4 p = *(const float4*)wr, q = *(const float4*)(wr + 4);
    short8v f;
    f[0] = (short)f2bf_bits(p.x); f[1] = (short)f2bf_bits(p.y);
    f[2] = (short)f2bf_bits(p.z); f[3] = (short)f2bf_bits(p.w);
    f[4] = (short)f2bf_bits(q.x); f[5] = (short)f2bf_bits(q.y);
    f[6] = (short)f2bf_bits(q.z); f[7] = (short)f2bf_bits(q.w);
    w1f[t] = f;
  }
  short8v w2f[4][4]; // A-frag: W2[ch=ct*16+ln][k=kt*32+kq*8+e]
  #pragma unroll
  for (int ct = 0; ct < 4; ++ct)
    #pragma unroll
    for (int kt = 0; kt < 4; ++kt) {
      const float* wr = W2 + (size_t)(ct * 16 + ln) * 128 + kt * 32 + kq * 8;
      float4 p = *(const float4*)wr, q = *(const float4*)(wr + 4);
      short8v f;
      f[0] = (short)f2bf_bits(p.x); f[1] = (short)f2bf_bits(p.y);
      f[2] = (short)f2bf_bits(p.z); f[3] = (short)f2bf_bits(p.w);
      f[4] = (short)f2bf_bits(q.x); f[5] = (short)f2bf_bits(q.y);
      f[6] = (short)f2bf_bits(q.z); f[7] = (short)f2bf_bits(q.w);
      w2f[ct][kt] = f;
    }
  float b2v[16];
  #pragma unroll
  for (int ct = 0; ct < 4; ++ct)
    #pragma unroll
    for (int i = 0; i < 4; ++i)
      b2v[ct * 4 + i] = b2[ct * 16 + kq * 4 + i];
  __syncthreads();   // only barrier: a1s/c1s staging

  const int gw = blockIdx.x * 4 + wv;
  const int t0 = gw * tpw;
  const int t1 = min(t0 + tpw, ntiles);
  if (t0 >= t1) return;

  unsigned short* br = &h1d[wv][0][0];
  unsigned short* bw = &h1d[wv][1][0];
  const f32x4 zero4 = {0.f, 0.f, 0.f, 0.f};

  auto loadT = [&](int t, float4& P, float4& Q, int& G) {
    const int node = min(t * 16 + ln, N - 1);
    const float* xr = x + (size_t)node * 32 + kq * 8;
    P = *(const float4*)xr; Q = *(const float4*)(xr + 4);
    G = gidx[node];
  };
  auto produce = [&](float4 P, float4 Q, int G, unsigned short* dst) {
    pk4 A;
    A.u[0] = cvtpk(P.x, P.y); A.u[1] = cvtpk(P.z, P.w);
    A.u[2] = cvtpk(Q.x, Q.y); A.u[3] = cvtpk(Q.z, Q.w);
    f32x4 acc1[8];
    #pragma unroll
    for (int tt = 0; tt < 8; ++tt)
      acc1[tt] = __builtin_amdgcn_mfma_f32_16x16x32_bf16(w1f[tt], A.v, zero4, 0, 0, 0);
    const float* ap = a1s + G * 128;
    const float* cp = c1s + G * 128;
    #pragma unroll
    for (int tt = 0; tt < 8; ++tt) {
      const int ch0 = tt * 16 + kq * 4;
      f32x4 av = *(const f32x4*)(ap + ch0);   // broadcast b128
      f32x4 cv = *(const f32x4*)(cp + ch0);
      float v0 = leaky(fmaf(acc1[tt][0], av[0], cv[0]));
      float v1 = leaky(fmaf(acc1[tt][1], av[1], cv[1]));
      float v2 = leaky(fmaf(acc1[tt][2], av[2], cv[2]));
      float v3 = leaky(fmaf(acc1[tt][3], av[3], cv[3]));
      uint2 w; w.x = cvtpk(v0, v1); w.y = cvtpk(v2, v3);
      const int off = (ln * 256 + ch0 * 2) ^ swz;   // bytes, 8B-aligned
      *(uint2*)&dst[off >> 1] = w;
    }
  };
  auto consume = [&](int t, const unsigned short* src) {
    short8v a2f[4];   // B-frag: h1n[node=ln][k=kt*32+kq*8+e]
    #pragma unroll
    for (int kt = 0; kt < 4; ++kt) {
      const int off = (ln * 256 + kt * 64 + kq * 16) ^ swz;
      a2f[kt] = *(const short8v*)&src[off >> 1];
    }
    f32x4 acc2[4];
    #pragma unroll
    for (int ct = 0; ct < 4; ++ct) {
      f32x4 a = zero4;
      #pragma unroll
      for (int kt = 0; kt < 4; ++kt)
        a = __builtin_amdgcn_mfma_f32_16x16x32_bf16(w2f[ct][kt], a2f[kt], a, 0, 0, 0);
      acc2[ct] = a;
    }
    const int node = t * 16 + ln;
    if (node < N) {
      unsigned short* orow = h2out + (size_t)node * 64;
      #pragma unroll
      for (int ct = 0; ct < 4; ++ct) {
        float u0 = acc2[ct][0] + b2v[ct * 4 + 0];
        float u1 = acc2[ct][1] + b2v[ct * 4 + 1];
        float u2 = acc2[ct][2] + b2v[ct * 4 + 2];
        float u3 = acc2[ct][3] + b2v[ct * 4 + 3];
        uint2 w; w.x = cvtpk(u0, u1); w.y = cvtpk(u2, u3);
        *(uint2*)&orow[ct * 16 + kq * 4] = w;
      }
    }
  };

  float4 p, q; int gv;
  loadT(t0, p, q, gv);
  float4 p2, q2; int gv2;
  loadT(min(t0 + 1, t1 - 1), p2, q2, gv2);
  produce(p, q, gv, br);
  #pragma unroll 1
  for (int t = t0; t < t1; ++t) {
    if (t + 1 < t1) {
      float4 p3, q3; int gv3;
      loadT(min(t + 2, t1 - 1), p3, q3, gv3);
      produce(p2, q2, gv2, bw);
      p2 = p3; q2 = q3; gv2 = gv3;
    }
    consume(t, br);
    unsigned short* tmp = br; br = bw; bw = tmp;
  }
}

// K4 (R10): layer-2 stats from stored bf16 h2 (consistent with what k5d
// normalizes). Wave per node range, lane = channel, run-length flush.
__global__ __launch_bounds__(256) void k4_stats2(
    const unsigned short* __restrict__ h2, const int* __restrict__ gidx,
    float* __restrict__ ws, int N) {
  const int tid = threadIdx.x;
  const int gw = blockIdx.x * 4 + (tid >> 6);
  const int lane = tid & 63;
  const int nwaves = gridDim.x * 4;
  const int npw = (N + nwaves - 1) / nwaves;
  const int n0 = gw * npw;
  const int n1 = min(n0 + npw, N);
  float s = 0.f, qq = 0.f;
  int curg = -1;
  if (n0 < n1) {
    const int nlast = n1 - 1;
    int g = gidx[n0];
    unsigned short hv = h2[(size_t)n0 * 64 + lane];
    #pragma unroll 1
    for (int n = n0; n < n1; ++n) {
      const int nn = min(n + 1, nlast);
      const int g2 = gidx[nn];
      const unsigned short hv2 = h2[(size_t)nn * 64 + lane];
      if (g != curg) {
        if (curg >= 0) {
          atomicAdd(ws + OFF_SUM2 + curg * 64 + lane, s);
          atomicAdd(ws + OFF_SQ2  + curg * 64 + lane, qq);
        }
        curg = g; s = 0.f; qq = 0.f;
      }
      const float v = __uint_as_float((unsigned int)hv << 16);
      s += v; qq = fmaf(v, v, qq);
      g = g2; hv = hv2;
    }
  }
  if (curg >= 0) {
    atomicAdd(ws + OFF_SUM2 + curg * 64 + lane, s);
    atomicAdd(ws + OFF_SQ2  + curg * 64 + lane, qq);
  }
}

// ---- scatter-max via counting-sort inverse index ----
__global__ void k5a_hist(const int* __restrict__ sidx, int* __restrict__ hist, int N) {
  int n = blockIdx.x * 256 + threadIdx.x;
  if (n < N) atomicAdd(&hist[sidx[n]], 1);
}

__global__ __launch_bounds__(256) void k5b_scan(
    const int* __restrict__ hist, int* __restrict__ offsets,
    int* __restrict__ cursor, int M, int N) {
  __shared__ int part[256];
  const int tid = threadIdx.x;
  const int chunk = (M + 255) / 256;
  const int lo = min(tid * chunk, M), hi = min(lo + chunk, M);
  int s = 0;
  for (int i = lo; i < hi; ++i) s += hist[i];
  part[tid] = s;
  __syncthreads();
  if (tid == 0) {
    int run = 0;
    for (int i = 0; i < 256; ++i) { int v = part[i]; part[i] = run; run += v; }
  }
  __syncthreads();
  int run = part[tid];
  for (int i = lo; i < hi; ++i) {
    int v = hist[i];
    offsets[i] = run; cursor[i] = run; run += v;
  }
  if (tid == 255) offsets[M] = N;
}

__global__ void k5c_perm(const int* __restrict__ sidx, const int* __restrict__ gidx,
                         int* __restrict__ cursor, int* __restrict__ perm, int N) {
  int n = blockIdx.x * 256 + threadIdx.x;
  if (n >= N) return;
  int sp = sidx[n];
  int pos = atomicAdd(&cursor[sp], 1);
  perm[pos] = (n << 4) | (gidx[n] & 15);
}

__global__ __launch_bounds__(256) void k5d_gather(
    const unsigned short* __restrict__ h2, const int* __restrict__ perm,
    const int* __restrict__ offsets, const float* __restrict__ ws,
    float* __restrict__ out, int M) {
  __shared__ float a2s[1024], c2s[1024];
  const int tid = threadIdx.x;
  for (int i = tid; i < 1024; i += 256) { a2s[i] = ws[OFF_A2 + i]; c2s[i] = ws[OFF_C2 + i]; }
  __syncthreads();
  const int seg = blockIdx.x * 4 + (tid >> 6);
  if (seg >= M) return;
  const int lane = tid & 63;
  const int lo = offsets[seg], hi = offsets[seg + 1];
  float acc = -3.402823466e38f;
  if (hi > lo) {
    const int last = hi - 1;
    int pc = perm[lo];
    unsigned short hc = h2[(size_t)(pc >> 4) * 64 + lane];
    int pn = perm[min(lo + 1, last)];
    #pragma unroll 1
    for (int i = lo; i < hi; ++i) {
      const unsigned short hn = h2[(size_t)(pn >> 4) * 64 + lane];
      const int pn2 = perm[min(i + 2, last)];
      const int g = pc & 15;
      const float v = __uint_as_float((unsigned int)hc << 16);
      float y = fmaf(v, a2s[g * 64 + lane], c2s[g * 64 + lane]);
      y = y >= 0.f ? y : y * SLOPE;
      acc = fmaxf(acc, y);
      pc = pn; hc = hn; pn = pn2;
    }
  }
  out[(size_t)seg * 64 + lane] = (hi > lo) ? acc : 0.0f;
}

// ---- fallback (atomic path) when ws too small for index arrays ----
__global__ __launch_bounds__(256) void k5_scatter(
    const unsigned int* __restrict__ h2, const int* __restrict__ gidx,
    const int* __restrict__ sidx, const float* __restrict__ ws,
    unsigned int* __restrict__ out, int N) {
  int t = blockIdx.x * 256 + threadIdx.x;
  int node = t >> 4;
  if (node >= N) return;
  int jq = t & 15, j = jq * 4;
  int g = gidx[node];
  int sp = sidx[node];
  float4 av = *(const float4*)(ws + OFF_A2 + g * 64 + j);
  float4 cv = *(const float4*)(ws + OFF_C2 + g * 64 + j);
  uint2 hv = *(const uint2*)(h2 + (size_t)node * 32 + jq * 2);
  float v0 = __uint_as_float(hv.x << 16);
  float v1 = __uint_as_float(hv.x & 0xFFFF0000u);
  float v2 = __uint_as_float(hv.y << 16);
  float v3 = __uint_as_float(hv.y & 0xFFFF0000u);
  v0 = fmaf(v0, av.x, cv.x); v0 = v0 >= 0.f ? v0 : v0 * SLOPE;
  v1 = fmaf(v1, av.y, cv.y); v1 = v1 >= 0.f ? v1 : v1 * SLOPE;
  v2 = fmaf(v2, av.z, cv.z); v2 = v2 >= 0.f ? v2 : v2 * SLOPE;
  v3 = fmaf(v3, av.w, cv.w); v3 = v3 >= 0.f ? v3 : v3 * SLOPE;
  unsigned int* o = out + (size_t)sp * 64 + j;
  atomicMax(o + 0, enc_f32(v0));
  atomicMax(o + 1, enc_f32(v1));
  atomicMax(o + 2, enc_f32(v2));
  atomicMax(o + 3, enc_f32(v3));
}

__global__ void k6_decode(unsigned int* __restrict__ o, int n) {
  int i = blockIdx.x * 256 + threadIdx.x;
  if (i >= n) return;
  unsigned int e = o[i];
  float f;
  if (e == 0u) f = 0.0f;
  else if (e & 0x80000000u) f = __uint_as_float(e ^ 0x80000000u);
  else f = __uint_as_float(~e);
  ((float*)o)[i] = f;
}

extern "C" void kernel_launch(void* const* d_in, const int* in_sizes, int n_in,
                              void* d_out, int out_size, void* d_ws, size_t ws_size,
                              hipStream_t stream) {
  const float* x   = (const float*)d_in[0];
  const float* W1  = (const float*)d_in[1];
  const float* b1  = (const float*)d_in[2];
  const float* g1  = (const float*)d_in[3];
  const float* be1 = (const float*)d_in[4];
  const float* W2  = (const float*)d_in[5];
  const float* b2  = (const float*)d_in[6];
  const float* g2  = (const float*)d_in[7];
  const float* be2 = (const float*)d_in[8];
  const int* gidx  = (const int*)d_in[9];
  const int* sidx  = (const int*)d_in[10];
  const int N = in_sizes[9];
  const int M = out_size / 64;
  float* ws = (float*)d_ws;
  unsigned short* h2 = (unsigned short*)((char*)d_ws + H2_BYTE_OFF);
  unsigned int* out_u = (unsigned int*)d_out;

  const size_t idx_off = (size_t)H2_BYTE_OFF + (size_t)N * 128;
  int* hist    = (int*)((char*)d_ws + idx_off);
  int* cursor  = hist + M;
  int* offsets = cursor + M;            // M+1 entries
  int* perm    = offsets + M + 1;
  const size_t needed_fast = idx_off + (size_t)(3 * M + 1 + N) * 4;
  const bool fast = (ws_size >= needed_fast);

  const int zmax = (M_FLOATS > M ? M_FLOATS : M);
  hipLaunchKernelGGL(k_zero_all, dim3((zmax + 255) / 256), dim3(256), 0, stream,
                     ws, hist, fast ? M : 0);
  hipLaunchKernelGGL(k1_mom, dim3(256), dim3(256), 0, stream, x, gidx, ws, N);
  hipLaunchKernelGGL(k2a_fin1, dim3(NGRAPH), dim3(128), 0, stream, W1, b1, g1, be1, ws);
  if (fast) {
    hipLaunchKernelGGL(k5a_hist, dim3((N + 255) / 256), dim3(256), 0, stream, sidx, hist, N);
    hipLaunchKernelGGL(k5b_scan, dim3(1), dim3(256), 0, stream, hist, offsets, cursor, M, N);
    hipLaunchKernelGGL(k5c_perm, dim3((N + 255) / 256), dim3(256), 0, stream,
                       sidx, gidx, cursor, perm, N);
  }
  const int ntiles = (N + 15) / 16;
  const int NW3 = 3072;                      // 3 blocks/CU at 48KB LDS
  const int tpw = (ntiles + NW3 - 1) / NW3;
  const int k3blocks = (ntiles + 4 * tpw - 1) / (4 * tpw);
  hipLaunchKernelGGL(k3_mfma, dim3(k3blocks), dim3(256), 0, stream,
                     x, W1, W2, b2, gidx, ws, h2, N, ntiles, tpw);
  hipLaunchKernelGGL(k4_stats2, dim3(512), dim3(256), 0, stream, h2, gidx, ws, N);
  hipLaunchKernelGGL(k2_fin, dim3((NGRAPH * 64 + 255) / 256), dim3(256), 0, stream,
                     ws, g2, be2, 64, OFF_SUM2, OFF_SQ2, OFF_A2, OFF_C2);
  if (fast) {
    hipLaunchKernelGGL(k5d_gather, dim3((M + 3) / 4), dim3(256), 0, stream,
                       h2, perm, offsets, ws, (float*)d_out, M);
  } else {
    hipLaunchKernelGGL(k_init_out, dim3((out_size + 255) / 256), dim3(256), 0, stream,
                       out_u, out_size);
    hipLaunchKernelGGL(k5_scatter, dim3((N * 16 + 255) / 256), dim3(256), 0, stream,
                       (const unsigned int*)h2, gidx, sidx, ws, out_u, N);
    hipLaunchKernelGGL(k6_decode, dim3((out_size + 255) / 256), dim3(256), 0, stream,
                       out_u, out_size);
  }
}